// Round 4
// baseline (324.480 us; speedup 1.0000x reference)
//
#include <hip/hip_runtime.h>
#include <hip/hip_bf16.h>
#include <stdint.h>

// ---------------------------------------------------------------------------
// SelectiveMixing: x->W1->silu->W2->(q,k,g); v=(x@Wv+bv)*sig(g);
// attn=softmax(qk^T/sqrt(D)); out=rmsnorm(mix*attn@v + (1-mix)*x)
// B=4, L=2048, D=1024, INNER=1536. All matmuls bf16 MFMA, f32 accum.
// gemmk: 128x128 tile, BK=32, 4 waves, ring-3 LDS (48KB -> 3 blocks/CU),
// counted vmcnt(4), 2-way-free LDS swizzle, bijective XCD block swizzle.
// ---------------------------------------------------------------------------

typedef __bf16 bf16x8 __attribute__((ext_vector_type(8)));
typedef float f32x4 __attribute__((ext_vector_type(4)));

__device__ __forceinline__ unsigned short f2bf(float f) {
    unsigned int u = __float_as_uint(f);
    u += 0x7fffu + ((u >> 16) & 1u);
    return (unsigned short)(u >> 16);
}
__device__ __forceinline__ float bf2f(unsigned short s) {
    return __uint_as_float(((unsigned int)s) << 16);
}
__device__ __forceinline__ void llds16(const void* g, void* l) {
    __builtin_amdgcn_global_load_lds(
        (const __attribute__((address_space(1))) void*)g,
        (__attribute__((address_space(3))) void*)l, 16, 0, 0);
}

// ---------------- elementwise: f32 -> bf16 (8 elems/thread) ----------------
__global__ __launch_bounds__(256) void cvt_f32_bf16(
    const float* __restrict__ in, unsigned short* __restrict__ out, long long n8) {
    long long i = (long long)blockIdx.x * 256 + threadIdx.x;
    if (i >= n8) return;
    float4 a = ((const float4*)in)[2 * i];
    float4 b = ((const float4*)in)[2 * i + 1];
    ushort4 p0, p1;
    p0.x = f2bf(a.x); p0.y = f2bf(a.y); p0.z = f2bf(a.z); p0.w = f2bf(a.w);
    p1.x = f2bf(b.x); p1.y = f2bf(b.y); p1.z = f2bf(b.z); p1.w = f2bf(b.w);
    ((ushort4*)out)[2 * i] = p0;
    ((ushort4*)out)[2 * i + 1] = p1;
}

// ---------------- transpose + convert: f32 [R][C] -> bf16 [C][R] -----------
__global__ __launch_bounds__(256) void transpose_cvt(
    const float* __restrict__ in, unsigned short* __restrict__ out, int R, int C) {
    __shared__ unsigned short tile[32][33];
    int c0 = blockIdx.x * 32, r0 = blockIdx.y * 32;
    int cc = threadIdx.x & 31, rr = threadIdx.x >> 5;
#pragma unroll
    for (int p = 0; p < 4; ++p) {
        int r = rr + p * 8;
        tile[r][cc] = f2bf(in[(size_t)(r0 + r) * C + c0 + cc]);
    }
    __syncthreads();
#pragma unroll
    for (int p = 0; p < 4; ++p) {
        int c = rr + p * 8;
        out[(size_t)(c0 + c) * R + r0 + cc] = tile[cc][c];
    }
}

// ---------------- transpose v: bf16 [8192][1024] -> vt [4][1024][2048] -----
__global__ __launch_bounds__(256) void transpose_v(
    const unsigned short* __restrict__ in, unsigned short* __restrict__ out) {
    __shared__ unsigned short tile[32][33];
    int d0 = blockIdx.x * 32, m0 = blockIdx.y * 32;
    int cc = threadIdx.x & 31, rr = threadIdx.x >> 5;
#pragma unroll
    for (int p = 0; p < 4; ++p) {
        int r = rr + p * 8;
        tile[r][cc] = in[(size_t)(m0 + r) * 1024 + d0 + cc];
    }
    __syncthreads();
    int b = m0 >> 11, l0 = m0 & 2047;
#pragma unroll
    for (int p = 0; p < 4; ++p) {
        int d = rr + p * 8;
        out[((size_t)b * 1024 + d0 + d) * 2048 + l0 + cc] = tile[cc][d];
    }
}

// ---------------- 128x128 ring-3 GEMM, C = A @ B^T, templated epilogue -----
// A: [M][K] bf16 row-major lda, B: [N][K] bf16 row-major ldb.
// 256 threads = 4 waves (2x2), 64x64 per wave. BK=32.
// LDS: 3 x (A 8KB + B 8KB) = 48KB static -> 3 blocks/CU.
// Swizzle: 16B slot s stored at s ^ ((row>>1)&3)  (2-way on reads = free).
// EPI 0: bf16 = silu(acc+bias[n])          EPI 1: bf16 = acc+bias[n]
// EPI 2: bf16 = (acc+bias[n])*sigmoid(gate[m*ldg+n])   (row-major)
// EPI 3: f32 = acc*scale (z-batched)       EPI 4: f32 = mix residual
template <int EPI>
__global__ __launch_bounds__(256, 3) void gemmk(
    const unsigned short* __restrict__ A, int lda, long long Abs,
    const unsigned short* __restrict__ B, int ldb, long long Bbs,
    int K,
    void* __restrict__ out, int ldo, long long Obs,
    const float* __restrict__ bias,
    const unsigned short* __restrict__ gate, int ldg,
    const float* __restrict__ xres, const float* __restrict__ mix,
    float scale, int gx) {
    __shared__ unsigned short lds[24576];  // 3 bufs x (A 4096 + B 4096) ushorts
    const int tid = threadIdx.x, lane = tid & 63, wid = tid >> 6;
    // bijective XCD swizzle (gridDim.x % 8 == 0 for all launches)
    const int nwg = gridDim.x;
    const int bswz = ((int)blockIdx.x & 7) * (nwg >> 3) + ((int)blockIdx.x >> 3);
    const int bx = bswz % gx, by = bswz / gx;
    const int bm = by * 128, bn = bx * 128;
    const int z = blockIdx.z;
    A += (long long)z * Abs;
    B += (long long)z * Bbs;
    const int NT = K >> 5;

    // staging: thread t -> row (t>>2) of 64-row chunk, 16B slot (t&3);
    // global slot pre-swizzled so LDS stays linear.
    const int srow = tid >> 2;
    const int sswz = ((tid & 3) ^ ((tid >> 3) & 3)) * 8;
    size_t ag[2], bg[2];
    ag[0] = (size_t)(bm + srow) * lda + sswz;
    ag[1] = (size_t)(bm + 64 + srow) * lda + sswz;
    bg[0] = (size_t)(bn + srow) * ldb + sswz;
    bg[1] = (size_t)(bn + 64 + srow) * ldb + sswz;
    const int wl = wid * 512;  // wave-uniform LDS base within a chunk

    auto stage = [&](int t, int bb) {
        const size_t k0 = (size_t)t << 5;
        llds16(A + ag[0] + k0, &lds[bb + wl]);
        llds16(A + ag[1] + k0, &lds[bb + 2048 + wl]);
        llds16(B + bg[0] + k0, &lds[bb + 4096 + wl]);
        llds16(B + bg[1] + k0, &lds[bb + 6144 + wl]);
    };

    // fragment read offsets (swizzled; (row>>1)&3 == (l15>>1)&3, lane-const)
    const int wr = wid >> 1, wc = wid & 1;
    const int l15 = lane & 15, g4 = lane >> 4;
    const int fswz = (g4 ^ ((l15 >> 1) & 3)) * 8;
    const int aoff = (wr * 64 + l15) * 32 + fswz;         // + i*512
    const int boff = 4096 + (wc * 64 + l15) * 32 + fswz;  // + j*512

    f32x4 acc[4][4] = {};

    // prologue: tiles 0,1 -> bufs 0,1
    stage(0, 0);
    stage(1, 8192);
    asm volatile("s_waitcnt vmcnt(4)" ::: "memory");  // tile 0 landed
    __builtin_amdgcn_s_barrier();

    int bb = 0;
    for (int t = 0; t < NT; ++t) {
        const bool st = (t + 2) < NT;
        if (st) {
            // buffer of tile t-1 (reads done before previous barrier)
            const int tgt = (bb >= 8192) ? bb - 8192 : bb + 16384;
            stage(t + 2, tgt);
        }
        __builtin_amdgcn_sched_barrier(0);  // staging issues first
        bf16x8 af[4], bf[4];
#pragma unroll
        for (int i = 0; i < 4; ++i) {
            af[i] = *(const bf16x8*)&lds[bb + aoff + i * 512];
            bf[i] = *(const bf16x8*)&lds[bb + boff + i * 512];
        }
#pragma unroll
        for (int i = 0; i < 4; ++i)
#pragma unroll
            for (int j = 0; j < 4; ++j)
                acc[i][j] = __builtin_amdgcn_mfma_f32_16x16x32_bf16(
                    af[i], bf[j], acc[i][j], 0, 0, 0);
        // this wave's ds_reads retired before anyone re-stages buf bb
        asm volatile("s_waitcnt lgkmcnt(0)" ::: "memory");
        if (st) asm volatile("s_waitcnt vmcnt(4)" ::: "memory");  // t+1 landed
        else    asm volatile("s_waitcnt vmcnt(0)" ::: "memory");
        __builtin_amdgcn_s_barrier();
        bb = (bb == 16384) ? 0 : bb + 8192;
    }

    const int row0 = bm + wr * 64, col0 = bn + wc * 64;
#pragma unroll
    for (int i = 0; i < 4; ++i) {
#pragma unroll
        for (int j = 0; j < 4; ++j) {
            const int n = col0 + j * 16 + l15;
            const int mb = row0 + i * 16 + g4 * 4;
            f32x4 v = acc[i][j];
            if constexpr (EPI == 0 || EPI == 1) {
                float bs = bias[n];
                unsigned short* o = (unsigned short*)out;
#pragma unroll
                for (int q = 0; q < 4; ++q) {
                    float val = v[q] + bs;
                    if constexpr (EPI == 0) val = val / (1.f + __expf(-val));
                    o[(size_t)(mb + q) * ldo + n] = f2bf(val);
                }
            } else if constexpr (EPI == 2) {
                float bs = bias[n];
                unsigned short* o = (unsigned short*)out;
#pragma unroll
                for (int q = 0; q < 4; ++q) {
                    int m = mb + q;
                    float g = bf2f(gate[(size_t)m * ldg + n]);
                    float val = (v[q] + bs) / (1.f + __expf(-g));
                    o[(size_t)m * ldo + n] = f2bf(val);
                }
            } else if constexpr (EPI == 3) {
                float* o = (float*)out + (size_t)z * Obs;
#pragma unroll
                for (int q = 0; q < 4; ++q)
                    o[(size_t)(mb + q) * ldo + n] = v[q] * scale;
            } else {  // EPI == 4
                float* o = (float*)out + (size_t)z * Obs;
                const float* xr = xres + (size_t)z * Obs;
                float mw = mix[n];
#pragma unroll
                for (int q = 0; q < 4; ++q)
                    o[(size_t)(mb + q) * ldo + n] =
                        mw * v[q] + (1.f - mw) * xr[(size_t)(mb + q) * ldo + n];
            }
        }
    }
}

// ---------------- row softmax, f32 in -> bf16 out, IN PLACE (row-aliased) --
__global__ __launch_bounds__(256) void softmax_inplace(float* __restrict__ scores) {
    const int L = 2048;
    float* sr = scores + (size_t)blockIdx.x * L;
    const int t = threadIdx.x, lane = t & 63, wid = t >> 6;
    float4 a = ((const float4*)sr)[2 * t];
    float4 b = ((const float4*)sr)[2 * t + 1];
    float vv[8] = {a.x, a.y, a.z, a.w, b.x, b.y, b.z, b.w};
    float mx = vv[0];
#pragma unroll
    for (int i = 1; i < 8; ++i) mx = fmaxf(mx, vv[i]);
#pragma unroll
    for (int off = 32; off; off >>= 1) mx = fmaxf(mx, __shfl_xor(mx, off));
    __shared__ float redm[4], reds[4];
    if (lane == 0) redm[wid] = mx;
    __syncthreads();
    mx = fmaxf(fmaxf(redm[0], redm[1]), fmaxf(redm[2], redm[3]));
    float s = 0.f;
#pragma unroll
    for (int i = 0; i < 8; ++i) {
        vv[i] = __expf(vv[i] - mx);
        s += vv[i];
    }
#pragma unroll
    for (int off = 32; off; off >>= 1) s += __shfl_xor(s, off);
    if (lane == 0) reds[wid] = s;
    __syncthreads();
    s = reds[0] + reds[1] + reds[2] + reds[3];
    float inv = 1.f / s;
    ushort4 p0, p1;
    unsigned short* pp0 = (unsigned short*)&p0;
    unsigned short* pp1 = (unsigned short*)&p1;
#pragma unroll
    for (int i = 0; i < 4; ++i) pp0[i] = f2bf(vv[i] * inv);
#pragma unroll
    for (int i = 0; i < 4; ++i) pp1[i] = f2bf(vv[4 + i] * inv);
    unsigned short* pr = (unsigned short*)sr;
    ((ushort4*)pr)[2 * t] = p0;
    ((ushort4*)pr)[2 * t + 1] = p1;
}

// ---------------- in-place RMSNorm over rows of D=1024 f32 ----------------
__global__ __launch_bounds__(256) void rmsnorm_inplace(
    float* __restrict__ io, const float* __restrict__ w) {
    const int D = 1024;
    float* r = io + (size_t)blockIdx.x * D;
    const int t = threadIdx.x, lane = t & 63, wid = t >> 6;
    float4 v = ((const float4*)r)[t];
    float ss = v.x * v.x + v.y * v.y + v.z * v.z + v.w * v.w;
#pragma unroll
    for (int off = 32; off; off >>= 1) ss += __shfl_xor(ss, off);
    __shared__ float red[4];
    if (lane == 0) red[wid] = ss;
    __syncthreads();
    ss = red[0] + red[1] + red[2] + red[3];
    float sc = rsqrtf(ss / (float)D + 1e-6f);
    float4 wv = ((const float4*)w)[t];
    v.x *= sc * wv.x; v.y *= sc * wv.y; v.z *= sc * wv.z; v.w *= sc * wv.w;
    ((float4*)r)[t] = v;
}

// ---------------------------------------------------------------------------
extern "C" void kernel_launch(void* const* d_in, const int* in_sizes, int n_in,
                              void* d_out, int out_size, void* d_ws, size_t ws_size,
                              hipStream_t stream) {
    const float* x = (const float*)d_in[0];
    const float* W1 = (const float*)d_in[1];
    const float* b1 = (const float*)d_in[2];
    const float* W2 = (const float*)d_in[3];
    const float* b2 = (const float*)d_in[4];
    const float* Wv = (const float*)d_in[5];
    const float* bv = (const float*)d_in[6];
    const float* mixw = (const float*)d_in[7];
    const float* normw = (const float*)d_in[8];
    float* out = (float*)d_out;

    const int L = 2048, D = 1024, INNER = 1536, BN4 = 4;
    const int M = BN4 * L;  // 8192

    // workspace carve (~191 MB total; v aliases the scores buffer)
    char* w = (char*)d_ws;
    auto carve = [&](size_t bytes) {
        void* p = (void*)w;
        w += (bytes + 255) & ~(size_t)255;
        return p;
    };
    unsigned short* xbf = (unsigned short*)carve((size_t)M * D * 2);
    unsigned short* w1t = (unsigned short*)carve((size_t)INNER * D * 2);
    unsigned short* w2t = (unsigned short*)carve((size_t)3 * D * INNER * 2);
    unsigned short* wvt = (unsigned short*)carve((size_t)D * D * 2);
    unsigned short* h = (unsigned short*)carve((size_t)M * INNER * 2);
    unsigned short* qkg = (unsigned short*)carve((size_t)M * 3 * D * 2);
    unsigned short* vt = (unsigned short*)carve((size_t)BN4 * D * L * 2);
    float* scores = (float*)carve((size_t)BN4 * L * L * 4);
    unsigned short* vtmp = (unsigned short*)scores;  // v row-major, dead after
                                                     // transpose_v (scores GEMM
                                                     // overwrites it later)

    // 1) x -> bf16
    cvt_f32_bf16<<<(M * D) / 2048, 256, 0, stream>>>(x, xbf, (long long)M * D / 8);
    // 2-4) weights -> bf16, transposed to [N][K]
    transpose_cvt<<<dim3(INNER / 32, D / 32), 256, 0, stream>>>(W1, w1t, D, INNER);
    transpose_cvt<<<dim3(3 * D / 32, INNER / 32), 256, 0, stream>>>(W2, w2t, INNER, 3 * D);
    transpose_cvt<<<dim3(D / 32, D / 32), 256, 0, stream>>>(Wv, wvt, D, D);
    // 5) h = silu(x @ W1 + b1)     [M][INNER] bf16   (768 blocks, gx=12)
    gemmk<0><<<dim3(768, 1, 1), 256, 0, stream>>>(
        xbf, D, 0, w1t, D, 0, D, h, INNER, 0, b1, nullptr, 0, nullptr, nullptr,
        1.f, 12);
    // 6) qkg = h @ W2 + b2         [M][3D] bf16      (1536 blocks, gx=24)
    gemmk<1><<<dim3(1536, 1, 1), 256, 0, stream>>>(
        h, INNER, 0, w2t, INNER, 0, INNER, qkg, 3 * D, 0, b2, nullptr, 0, nullptr,
        nullptr, 1.f, 24);
    // 7) v = (x @ Wv + bv) * sigmoid(g)   [M][D] bf16 row-major (512, gx=8)
    gemmk<2><<<dim3(512, 1, 1), 256, 0, stream>>>(
        xbf, D, 0, wvt, D, 0, D, vtmp, D, 0, bv, qkg + 2 * D, 3 * D, nullptr,
        nullptr, 1.f, 8);
    // 7b) vt = v^T per batch  [B][D][L]
    transpose_v<<<dim3(D / 32, M / 32), 256, 0, stream>>>(vtmp, vt);
    // 8) scores = q @ k^T / 32     [B][L][L] f32     (256 x 4 blocks, gx=16)
    gemmk<3><<<dim3(256, 1, BN4), 256, 0, stream>>>(
        qkg, 3 * D, (long long)L * 3 * D, qkg + D, 3 * D, (long long)L * 3 * D, D,
        scores, L, (long long)L * L, nullptr, nullptr, 0, nullptr, nullptr,
        0.03125f, 16);
    // 9) softmax rows, write bf16 P in place (row pitch 2L ushorts)
    softmax_inplace<<<BN4 * L, 256, 0, stream>>>(scores);
    // 10) out = mix * (P @ vT^T) + (1-mix) * x   [B][L][D] f32 (128 x 4, gx=8)
    gemmk<4><<<dim3(128, 1, BN4), 256, 0, stream>>>(
        (const unsigned short*)scores, 2 * L, (long long)L * 2 * L, vt, L,
        (long long)D * L, L, out, D, (long long)L * D, nullptr, nullptr, 0, x,
        mixw, 1.f, 8);
    // 11) in-place rmsnorm
    rmsnorm_inplace<<<M, 256, 0, stream>>>(out, normw);
}

// Round 5
// 291.061 us; speedup vs baseline: 1.1148x; 1.1148x over previous
//
#include <hip/hip_runtime.h>
#include <hip/hip_bf16.h>
#include <stdint.h>

// ---------------------------------------------------------------------------
// SelectiveMixing: x->W1->silu->W2->(q,k,g); v=(x@Wv+bv)*sig(g);
// attn=softmax(qk^T/sqrt(D)); out=rmsnorm(mix*attn@v + (1-mix)*x)
// B=4, L=2048, D=1024, INNER=1536. All matmuls bf16 MFMA, f32 accum.
// gemm5: 256x128 8-phase-style pipelined GEMM, counted vmcnt(4), parity
//        double-buffer, XOR-swizzled LDS. Packs 256/512/768-block grids.
// gemmk: 128x128 ring-3 GEMM for GEMM1 (N=1536 doesn't tile by 256).
// ---------------------------------------------------------------------------

typedef __bf16 bf16x8 __attribute__((ext_vector_type(8)));
typedef float f32x4 __attribute__((ext_vector_type(4)));

#define VM4 asm volatile("s_waitcnt vmcnt(4)" ::: "memory")
#define VM2 asm volatile("s_waitcnt vmcnt(2)" ::: "memory")
#define VM0 asm volatile("s_waitcnt vmcnt(0)" ::: "memory")
#define LGKM0 asm volatile("s_waitcnt lgkmcnt(0)" ::: "memory")
#define BAR __builtin_amdgcn_s_barrier()
#define SCB __builtin_amdgcn_sched_barrier(0)

__device__ __forceinline__ unsigned short f2bf(float f) {
    unsigned int u = __float_as_uint(f);
    u += 0x7fffu + ((u >> 16) & 1u);
    return (unsigned short)(u >> 16);
}
__device__ __forceinline__ float bf2f(unsigned short s) {
    return __uint_as_float(((unsigned int)s) << 16);
}
__device__ __forceinline__ void llds16(const void* g, void* l) {
    __builtin_amdgcn_global_load_lds(
        (const __attribute__((address_space(1))) void*)g,
        (__attribute__((address_space(3))) void*)l, 16, 0, 0);
}
__device__ __forceinline__ f32x4 MF(bf16x8 a, bf16x8 b, f32x4 c) {
    return __builtin_amdgcn_mfma_f32_16x16x32_bf16(a, b, c, 0, 0, 0);
}

// ---------------- elementwise: f32 -> bf16 (8 elems/thread) ----------------
__global__ __launch_bounds__(256) void cvt_f32_bf16(
    const float* __restrict__ in, unsigned short* __restrict__ out, long long n8) {
    long long i = (long long)blockIdx.x * 256 + threadIdx.x;
    if (i >= n8) return;
    float4 a = ((const float4*)in)[2 * i];
    float4 b = ((const float4*)in)[2 * i + 1];
    ushort4 p0, p1;
    p0.x = f2bf(a.x); p0.y = f2bf(a.y); p0.z = f2bf(a.z); p0.w = f2bf(a.w);
    p1.x = f2bf(b.x); p1.y = f2bf(b.y); p1.z = f2bf(b.z); p1.w = f2bf(b.w);
    ((ushort4*)out)[2 * i] = p0;
    ((ushort4*)out)[2 * i + 1] = p1;
}

// ---------------- transpose + convert: f32 [R][C] -> bf16 [C][R] -----------
__global__ __launch_bounds__(256) void transpose_cvt(
    const float* __restrict__ in, unsigned short* __restrict__ out, int R, int C) {
    __shared__ unsigned short tile[32][33];
    int c0 = blockIdx.x * 32, r0 = blockIdx.y * 32;
    int cc = threadIdx.x & 31, rr = threadIdx.x >> 5;
#pragma unroll
    for (int p = 0; p < 4; ++p) {
        int r = rr + p * 8;
        tile[r][cc] = f2bf(in[(size_t)(r0 + r) * C + c0 + cc]);
    }
    __syncthreads();
#pragma unroll
    for (int p = 0; p < 4; ++p) {
        int c = rr + p * 8;
        out[(size_t)(c0 + c) * R + r0 + cc] = tile[cc][c];
    }
}

// ---------------- gemm5: 256x128 pipelined GEMM, C = A @ B^T ---------------
// A: [M][K] bf16 row-major lda, B: [N][K] bf16 row-major ldb. BK=64.
// 512 threads = 8 waves (4 row x 2 col), wave tile 64x64.
// LDS: parity buffers X (even K-tiles) / Y (odd), each A 32KB + B 16KB.
// 4 phases per 2-tile iteration: F0{X: Ball+A01}, F1{X: A23},
// F2{Y: Ball+A01}, F3{Y: A23}. Stage units (2 loads/thread each):
// F0:A01(t+1->Y)  F1:A23(t+1->Y),B(t+2->X)  F2:A01(t+2->X)
// F3:A23(t+2->X),B(t+3->Y). Per-wave FIFO ledger => vmcnt(4) at every
// phase end (2 units float); last iteration peels to vmcnt(2)/vmcnt(0).
// EPI 1: bf16 = acc+bias[n]
// EPI 2: vT bf16: out[(m>>11)*1024+n][m&2047] = (acc+bias[n])*sigmoid(gate)
// EPI 3: f32 = acc*scale (z-batched)
// EPI 4: f32 = mix[n]*acc + (1-mix[n])*xres (z-batched)
template <int EPI>
__global__ __launch_bounds__(512, 1) void gemm5(
    const unsigned short* __restrict__ A, int lda, long long Abs,
    const unsigned short* __restrict__ B, int ldb, long long Bbs,
    int K,
    void* __restrict__ out, int ldo, long long Obs,
    const float* __restrict__ bias,
    const unsigned short* __restrict__ gate, int ldg,
    const float* __restrict__ xres, const float* __restrict__ mix,
    float scale, int gx) {
    __shared__ unsigned short lds[49152];  // X @0, Y @24576 (ushorts)
    const int tid = threadIdx.x, lane = tid & 63, wid = tid >> 6;
    const int wr = wid >> 1, wc = wid & 1;
    const int nwg = gridDim.x;
    const int bswz = ((int)blockIdx.x & 7) * (nwg >> 3) + ((int)blockIdx.x >> 3);
    const int bx = bswz % gx, by = bswz / gx;
    const int bm = by * 256, bn = bx * 128;
    const int z = blockIdx.z;
    A += (long long)z * Abs;
    B += (long long)z * Bbs;
    const int NT = K >> 6;  // even, >= 2

    // staging: thread t covers LDS slot t*16B of each 4096-ushort chunk
    // (row t>>3, 16B slot t&7); global source slot pre-swizzled by row&7.
    const int sswz = ((tid & 7) ^ ((tid >> 3) & 7)) * 8;
    size_t agc[4], bgc[2];
#pragma unroll
    for (int c = 0; c < 4; ++c)
        agc[c] = (size_t)(bm + c * 64 + (tid >> 3)) * lda + sswz;
#pragma unroll
    for (int c = 0; c < 2; ++c)
        bgc[c] = (size_t)(bn + c * 64 + (tid >> 3)) * ldb + sswz;
    const int wl = wid * 512;  // wave-uniform base within a chunk

    auto stA01 = [&](int t, int buf) {
        const size_t k0 = (size_t)t << 6;
        llds16(A + agc[0] + k0, &lds[buf + wl]);
        llds16(A + agc[1] + k0, &lds[buf + 4096 + wl]);
    };
    auto stA23 = [&](int t, int buf) {
        const size_t k0 = (size_t)t << 6;
        llds16(A + agc[2] + k0, &lds[buf + 8192 + wl]);
        llds16(A + agc[3] + k0, &lds[buf + 12288 + wl]);
    };
    auto stB = [&](int t, int buf) {
        const size_t k0 = (size_t)t << 6;
        llds16(B + bgc[0] + k0, &lds[buf + 16384 + wl]);
        llds16(B + bgc[1] + k0, &lds[buf + 20480 + wl]);
    };

    // fragment read offsets (LDS slot = global slot ^ (row&7); row&7==l7)
    const int l15 = lane & 15, g4 = lane >> 4, l7 = lane & 7;
    const int x0 = (g4 ^ l7) * 8, x1 = ((4 + g4) ^ l7) * 8;
    const int ab = (wr * 64 + l15) * 64;           // A: + i*1024 + xs
    const int bbv = 16384 + (wc * 64 + l15) * 64;  // B: + j*1024 + xs
    constexpr int X = 0, Y = 24576;

    f32x4 acc[4][4] = {};

    // prologue: full tile0 -> X, B(tile1) -> Y; leaves {A23(0),B(1)} in flight
    stB(0, X); stA01(0, X); stA23(0, X); stB(1, Y);
    VM4;  // B(0)+A01(0) landed
    BAR; SCB;

    int t = 0;
    while (true) {
        const bool last = (t + 2) >= NT;
        bf16x8 bf[4][2], af[2][2];
        // ---- F0: X: B all + A frags 0,1 ; stage A01(t+1 -> Y)
#pragma unroll
        for (int j = 0; j < 4; ++j) {
            bf[j][0] = *(const bf16x8*)&lds[X + bbv + j * 1024 + x0];
            bf[j][1] = *(const bf16x8*)&lds[X + bbv + j * 1024 + x1];
        }
#pragma unroll
        for (int i = 0; i < 2; ++i) {
            af[i][0] = *(const bf16x8*)&lds[X + ab + i * 1024 + x0];
            af[i][1] = *(const bf16x8*)&lds[X + ab + i * 1024 + x1];
        }
        stA01(t + 1, Y);
        LGKM0; SCB;
        __builtin_amdgcn_s_setprio(1);
#pragma unroll
        for (int s = 0; s < 2; ++s)
#pragma unroll
            for (int i = 0; i < 2; ++i)
#pragma unroll
                for (int j = 0; j < 4; ++j)
                    acc[i][j] = MF(af[i][s], bf[j][s], acc[i][j]);
        __builtin_amdgcn_s_setprio(0);
        VM4;  // A23(t) landed; {B(t+1),A01(t+1)} float
        BAR; SCB;
        // ---- F1: X: A frags 2,3 ; stage A23(t+1->Y), B(t+2->X)
#pragma unroll
        for (int i = 0; i < 2; ++i) {
            af[i][0] = *(const bf16x8*)&lds[X + ab + (2 + i) * 1024 + x0];
            af[i][1] = *(const bf16x8*)&lds[X + ab + (2 + i) * 1024 + x1];
        }
        stA23(t + 1, Y);
        if (!last) stB(t + 2, X);
        LGKM0; SCB;
        __builtin_amdgcn_s_setprio(1);
#pragma unroll
        for (int s = 0; s < 2; ++s)
#pragma unroll
            for (int i = 0; i < 2; ++i)
#pragma unroll
                for (int j = 0; j < 4; ++j)
                    acc[2 + i][j] = MF(af[i][s], bf[j][s], acc[2 + i][j]);
        __builtin_amdgcn_s_setprio(0);
        if (last) { VM2; } else { VM4; }  // B(t+1)+A01(t+1) landed
        BAR; SCB;
        // ---- F2: Y: B all + A frags 0,1 ; stage A01(t+2 -> X)
#pragma unroll
        for (int j = 0; j < 4; ++j) {
            bf[j][0] = *(const bf16x8*)&lds[Y + bbv + j * 1024 + x0];
            bf[j][1] = *(const bf16x8*)&lds[Y + bbv + j * 1024 + x1];
        }
#pragma unroll
        for (int i = 0; i < 2; ++i) {
            af[i][0] = *(const bf16x8*)&lds[Y + ab + i * 1024 + x0];
            af[i][1] = *(const bf16x8*)&lds[Y + ab + i * 1024 + x1];
        }
        if (!last) stA01(t + 2, X);
        LGKM0; SCB;
        __builtin_amdgcn_s_setprio(1);
#pragma unroll
        for (int s = 0; s < 2; ++s)
#pragma unroll
            for (int i = 0; i < 2; ++i)
#pragma unroll
                for (int j = 0; j < 4; ++j)
                    acc[i][j] = MF(af[i][s], bf[j][s], acc[i][j]);
        __builtin_amdgcn_s_setprio(0);
        if (last) { VM0; } else { VM4; }  // A23(t+1) landed
        BAR; SCB;
        // ---- F3: Y: A frags 2,3 ; stage A23(t+2->X), B(t+3->Y)
#pragma unroll
        for (int i = 0; i < 2; ++i) {
            af[i][0] = *(const bf16x8*)&lds[Y + ab + (2 + i) * 1024 + x0];
            af[i][1] = *(const bf16x8*)&lds[Y + ab + (2 + i) * 1024 + x1];
        }
        if (!last) { stA23(t + 2, X); stB(t + 3, Y); }
        LGKM0; SCB;
        __builtin_amdgcn_s_setprio(1);
#pragma unroll
        for (int s = 0; s < 2; ++s)
#pragma unroll
            for (int i = 0; i < 2; ++i)
#pragma unroll
                for (int j = 0; j < 4; ++j)
                    acc[2 + i][j] = MF(af[i][s], bf[j][s], acc[2 + i][j]);
        __builtin_amdgcn_s_setprio(0);
        if (last) break;
        VM4;  // B(t+2)+A01(t+2) landed
        BAR; SCB;
        t += 2;
    }

    // --- epilogue
    const int row0 = bm + wr * 64, col0 = bn + wc * 64;
#pragma unroll
    for (int i = 0; i < 4; ++i) {
#pragma unroll
        for (int j = 0; j < 4; ++j) {
            const int n = col0 + j * 16 + l15;
            const int mb = row0 + i * 16 + g4 * 4;
            f32x4 v = acc[i][j];
            if constexpr (EPI == 1) {
                float bs = bias[n];
                unsigned short* o = (unsigned short*)out;
#pragma unroll
                for (int q = 0; q < 4; ++q)
                    o[(size_t)(mb + q) * ldo + n] = f2bf(v[q] + bs);
            } else if constexpr (EPI == 2) {
                float bs = bias[n];
                ushort4 pk;
                unsigned short* pku = (unsigned short*)&pk;
#pragma unroll
                for (int q = 0; q < 4; ++q) {
                    int m = mb + q;
                    float g = bf2f(gate[(size_t)m * ldg + n]);
                    pku[q] = f2bf((v[q] + bs) / (1.f + __expf(-g)));
                }
                unsigned short* o = (unsigned short*)out;
                size_t oi = ((size_t)(mb >> 11) * 1024 + n) * 2048 + (mb & 2047);
                *(ushort4*)(o + oi) = pk;
            } else if constexpr (EPI == 3) {
                float* o = (float*)out + (size_t)z * Obs;
#pragma unroll
                for (int q = 0; q < 4; ++q)
                    o[(size_t)(mb + q) * ldo + n] = v[q] * scale;
            } else {  // EPI == 4
                float* o = (float*)out + (size_t)z * Obs;
                const float* xr = xres + (size_t)z * Obs;
                float mw = mix[n];
#pragma unroll
                for (int q = 0; q < 4; ++q)
                    o[(size_t)(mb + q) * ldo + n] =
                        mw * v[q] + (1.f - mw) * xr[(size_t)(mb + q) * ldo + n];
            }
        }
    }
}

// ---------------- gemmk: 128x128 ring-3 GEMM (GEMM1 only) ------------------
// EPI 0: bf16 = silu(acc + bias[n])
template <int EPI>
__global__ __launch_bounds__(256, 3) void gemmk(
    const unsigned short* __restrict__ A, int lda,
    const unsigned short* __restrict__ B, int ldb,
    int K, void* __restrict__ out, int ldo,
    const float* __restrict__ bias, int gx) {
    __shared__ unsigned short lds[24576];
    const int tid = threadIdx.x, lane = tid & 63, wid = tid >> 6;
    const int nwg = gridDim.x;
    const int bswz = ((int)blockIdx.x & 7) * (nwg >> 3) + ((int)blockIdx.x >> 3);
    const int bx = bswz % gx, by = bswz / gx;
    const int bm = by * 128, bn = bx * 128;
    const int NT = K >> 5;

    const int srow = tid >> 2;
    const int sswz = ((tid & 3) ^ ((tid >> 3) & 3)) * 8;
    size_t ag[2], bg[2];
    ag[0] = (size_t)(bm + srow) * lda + sswz;
    ag[1] = (size_t)(bm + 64 + srow) * lda + sswz;
    bg[0] = (size_t)(bn + srow) * ldb + sswz;
    bg[1] = (size_t)(bn + 64 + srow) * ldb + sswz;
    const int wl = wid * 512;

    auto stage = [&](int t, int bb) {
        const size_t k0 = (size_t)t << 5;
        llds16(A + ag[0] + k0, &lds[bb + wl]);
        llds16(A + ag[1] + k0, &lds[bb + 2048 + wl]);
        llds16(B + bg[0] + k0, &lds[bb + 4096 + wl]);
        llds16(B + bg[1] + k0, &lds[bb + 6144 + wl]);
    };

    const int wr = wid >> 1, wc = wid & 1;
    const int l15 = lane & 15, g4 = lane >> 4;
    const int fswz = (g4 ^ ((l15 >> 1) & 3)) * 8;
    const int aoff = (wr * 64 + l15) * 32 + fswz;
    const int boff = 4096 + (wc * 64 + l15) * 32 + fswz;

    f32x4 acc[4][4] = {};
    stage(0, 0);
    stage(1, 8192);
    VM4; BAR;

    int bb = 0;
    for (int t = 0; t < NT; ++t) {
        const bool st = (t + 2) < NT;
        if (st) {
            const int tgt = (bb >= 8192) ? bb - 8192 : bb + 16384;
            stage(t + 2, tgt);
        }
        SCB;
        bf16x8 af[4], bf[4];
#pragma unroll
        for (int i = 0; i < 4; ++i) {
            af[i] = *(const bf16x8*)&lds[bb + aoff + i * 512];
            bf[i] = *(const bf16x8*)&lds[bb + boff + i * 512];
        }
#pragma unroll
        for (int i = 0; i < 4; ++i)
#pragma unroll
            for (int j = 0; j < 4; ++j)
                acc[i][j] = MF(af[i], bf[j], acc[i][j]);
        LGKM0;
        if (st) { VM4; } else { VM0; }
        BAR;
        bb = (bb == 16384) ? 0 : bb + 8192;
    }

    const int row0 = bm + wr * 64, col0 = bn + wc * 64;
#pragma unroll
    for (int i = 0; i < 4; ++i) {
#pragma unroll
        for (int j = 0; j < 4; ++j) {
            const int n = col0 + j * 16 + l15;
            const int mb = row0 + i * 16 + g4 * 4;
            f32x4 v = acc[i][j];
            float bs = bias[n];
            unsigned short* o = (unsigned short*)out;
#pragma unroll
            for (int q = 0; q < 4; ++q) {
                float val = v[q] + bs;
                if constexpr (EPI == 0) val = val / (1.f + __expf(-val));
                o[(size_t)(mb + q) * ldo + n] = f2bf(val);
            }
        }
    }
}

// ---------------- row softmax, f32 in -> bf16 out, IN PLACE (row-aliased) --
__global__ __launch_bounds__(256) void softmax_inplace(float* __restrict__ scores) {
    const int L = 2048;
    float* sr = scores + (size_t)blockIdx.x * L;
    const int t = threadIdx.x, lane = t & 63, wid = t >> 6;
    float4 a = ((const float4*)sr)[2 * t];
    float4 b = ((const float4*)sr)[2 * t + 1];
    float vv[8] = {a.x, a.y, a.z, a.w, b.x, b.y, b.z, b.w};
    float mx = vv[0];
#pragma unroll
    for (int i = 1; i < 8; ++i) mx = fmaxf(mx, vv[i]);
#pragma unroll
    for (int off = 32; off; off >>= 1) mx = fmaxf(mx, __shfl_xor(mx, off));
    __shared__ float redm[4], reds[4];
    if (lane == 0) redm[wid] = mx;
    __syncthreads();
    mx = fmaxf(fmaxf(redm[0], redm[1]), fmaxf(redm[2], redm[3]));
    float s = 0.f;
#pragma unroll
    for (int i = 0; i < 8; ++i) {
        vv[i] = __expf(vv[i] - mx);
        s += vv[i];
    }
#pragma unroll
    for (int off = 32; off; off >>= 1) s += __shfl_xor(s, off);
    if (lane == 0) reds[wid] = s;
    __syncthreads();
    s = reds[0] + reds[1] + reds[2] + reds[3];
    float inv = 1.f / s;
    ushort4 p0, p1;
    unsigned short* pp0 = (unsigned short*)&p0;
    unsigned short* pp1 = (unsigned short*)&p1;
#pragma unroll
    for (int i = 0; i < 4; ++i) pp0[i] = f2bf(vv[i] * inv);
#pragma unroll
    for (int i = 0; i < 4; ++i) pp1[i] = f2bf(vv[4 + i] * inv);
    unsigned short* pr = (unsigned short*)sr;
    ((ushort4*)pr)[2 * t] = p0;
    ((ushort4*)pr)[2 * t + 1] = p1;
}

// ---------------- in-place RMSNorm over rows of D=1024 f32 ----------------
__global__ __launch_bounds__(256) void rmsnorm_inplace(
    float* __restrict__ io, const float* __restrict__ w) {
    const int D = 1024;
    float* r = io + (size_t)blockIdx.x * D;
    const int t = threadIdx.x, lane = t & 63, wid = t >> 6;
    float4 v = ((const float4*)r)[t];
    float ss = v.x * v.x + v.y * v.y + v.z * v.z + v.w * v.w;
#pragma unroll
    for (int off = 32; off; off >>= 1) ss += __shfl_xor(ss, off);
    __shared__ float red[4];
    if (lane == 0) red[wid] = ss;
    __syncthreads();
    ss = red[0] + red[1] + red[2] + red[3];
    float sc = rsqrtf(ss / (float)D + 1e-6f);
    float4 wv = ((const float4*)w)[t];
    v.x *= sc * wv.x; v.y *= sc * wv.y; v.z *= sc * wv.z; v.w *= sc * wv.w;
    ((float4*)r)[t] = v;
}

// ---------------------------------------------------------------------------
extern "C" void kernel_launch(void* const* d_in, const int* in_sizes, int n_in,
                              void* d_out, int out_size, void* d_ws, size_t ws_size,
                              hipStream_t stream) {
    const float* x = (const float*)d_in[0];
    const float* W1 = (const float*)d_in[1];
    const float* b1 = (const float*)d_in[2];
    const float* W2 = (const float*)d_in[3];
    const float* b2 = (const float*)d_in[4];
    const float* Wv = (const float*)d_in[5];
    const float* bv = (const float*)d_in[6];
    const float* mixw = (const float*)d_in[7];
    const float* normw = (const float*)d_in[8];
    float* out = (float*)d_out;

    const int L = 2048, D = 1024, INNER = 1536, BN4 = 4;
    const int M = BN4 * L;  // 8192

    // workspace carve (~191 MB total)
    char* w = (char*)d_ws;
    auto carve = [&](size_t bytes) {
        void* p = (void*)w;
        w += (bytes + 255) & ~(size_t)255;
        return p;
    };
    unsigned short* xbf = (unsigned short*)carve((size_t)M * D * 2);
    unsigned short* w1t = (unsigned short*)carve((size_t)INNER * D * 2);
    unsigned short* w2t = (unsigned short*)carve((size_t)3 * D * INNER * 2);
    unsigned short* wvt = (unsigned short*)carve((size_t)D * D * 2);
    unsigned short* h = (unsigned short*)carve((size_t)M * INNER * 2);
    unsigned short* qkg = (unsigned short*)carve((size_t)M * 3 * D * 2);
    unsigned short* vt = (unsigned short*)carve((size_t)BN4 * D * L * 2);
    float* scores = (float*)carve((size_t)BN4 * L * L * 4);

    // 1) x -> bf16
    cvt_f32_bf16<<<(M * D) / 2048, 256, 0, stream>>>(x, xbf, (long long)M * D / 8);
    // 2-4) weights -> bf16, transposed to [N][K]
    transpose_cvt<<<dim3(INNER / 32, D / 32), 256, 0, stream>>>(W1, w1t, D, INNER);
    transpose_cvt<<<dim3(3 * D / 32, INNER / 32), 256, 0, stream>>>(W2, w2t, INNER, 3 * D);
    transpose_cvt<<<dim3(D / 32, D / 32), 256, 0, stream>>>(Wv, wvt, D, D);
    // 5) h = silu(x @ W1 + b1)     [M][INNER] bf16   (768 blocks, 3/CU)
    gemmk<0><<<dim3(768, 1, 1), 256, 0, stream>>>(xbf, D, w1t, D, D, h, INNER,
                                                  b1, 12);
    // 6) qkg = h @ W2 + b2         [M][3D] bf16      (768 blocks = 3 waves)
    gemm5<1><<<dim3(768, 1, 1), 512, 0, stream>>>(
        h, INNER, 0, w2t, INNER, 0, INNER, qkg, 3 * D, 0, b2, nullptr, 0,
        nullptr, nullptr, 1.f, 24);
    // 7) vT = ((x @ Wv + bv)*sigmoid(g))^T  [B][D][L] bf16  (256 blocks)
    gemm5<2><<<dim3(256, 1, 1), 512, 0, stream>>>(
        xbf, D, 0, wvt, D, 0, D, vt, L, 0, bv, qkg + 2 * D, 3 * D, nullptr,
        nullptr, 1.f, 8);
    // 8) scores = q @ k^T / 32     [B][L][L] f32     (128 x 4 = 512 blocks)
    gemm5<3><<<dim3(128, 1, BN4), 512, 0, stream>>>(
        qkg, 3 * D, (long long)L * 3 * D, qkg + D, 3 * D, (long long)L * 3 * D,
        D, scores, L, (long long)L * L, nullptr, nullptr, 0, nullptr, nullptr,
        0.03125f, 16);
    // 9) softmax rows, write bf16 P in place (row pitch 2L ushorts)
    softmax_inplace<<<BN4 * L, 256, 0, stream>>>(scores);
    // 10) out = mix * (P @ vT^T) + (1-mix) * x  [B][L][D] f32 (64 x 4 = 256)
    gemm5<4><<<dim3(64, 1, BN4), 512, 0, stream>>>(
        (const unsigned short*)scores, 2 * L, (long long)L * 2 * L, vt, L,
        (long long)D * L, L, out, D, (long long)L * D, nullptr, nullptr, 0, x,
        mixw, 1.f, 8);
    // 11) in-place rmsnorm
    rmsnorm_inplace<<<M, 256, 0, stream>>>(out, normw);
}

// Round 7
// 282.274 us; speedup vs baseline: 1.1495x; 1.0311x over previous
//
#include <hip/hip_runtime.h>
#include <hip/hip_bf16.h>
#include <stdint.h>

// ---------------------------------------------------------------------------
// SelectiveMixing: x->W1->silu->W2->(q,k,g); v=(x@Wv+bv)*sig(g);
// attn=softmax(qk^T/sqrt(D)); out=rmsnorm(mix*attn@v + (1-mix)*x)
// B=4, L=2048, D=1024, INNER=1536. All matmuls bf16 MFMA, f32 accum.
// Softmax FUSED into the GEMMs: scores GEMM writes P' = exp(s - B_z) bf16
// (B_z = per-batch Cauchy-Schwarz bound >= s, so exp never overflows) and
// atomically accumulates f32 row sums l; PV applies 1/l in its epilogue.
// RULE (learned round 6): inside gemm5's counted-vmcnt region NO other VMEM
// op may issue — all epilogue-only global loads happen after the final
// "memory"-clobbered waitcnt, never in the prologue.
// ---------------------------------------------------------------------------

typedef __bf16 bf16x8 __attribute__((ext_vector_type(8)));
typedef float f32x4 __attribute__((ext_vector_type(4)));

#define VM4 asm volatile("s_waitcnt vmcnt(4)" ::: "memory")
#define VM2 asm volatile("s_waitcnt vmcnt(2)" ::: "memory")
#define VM0 asm volatile("s_waitcnt vmcnt(0)" ::: "memory")
#define LGKM0 asm volatile("s_waitcnt lgkmcnt(0)" ::: "memory")
#define BAR __builtin_amdgcn_s_barrier()
#define SCB __builtin_amdgcn_sched_barrier(0)

__device__ __forceinline__ unsigned short f2bf(float f) {
    unsigned int u = __float_as_uint(f);
    u += 0x7fffu + ((u >> 16) & 1u);
    return (unsigned short)(u >> 16);
}
__device__ __forceinline__ float bf2f(unsigned short s) {
    return __uint_as_float(((unsigned int)s) << 16);
}
__device__ __forceinline__ void llds16(const void* g, void* l) {
    __builtin_amdgcn_global_load_lds(
        (const __attribute__((address_space(1))) void*)g,
        (__attribute__((address_space(3))) void*)l, 16, 0, 0);
}
__device__ __forceinline__ f32x4 MF(bf16x8 a, bf16x8 b, f32x4 c) {
    return __builtin_amdgcn_mfma_f32_16x16x32_bf16(a, b, c, 0, 0, 0);
}

// ---------------- zero fill ------------------------------------------------
__global__ __launch_bounds__(256) void zero_f32(float* __restrict__ p, int n) {
    int i = blockIdx.x * 256 + threadIdx.x;
    if (i < n) p[i] = 0.f;
}

// ---------------- elementwise: f32 -> bf16 (8 elems/thread) ----------------
__global__ __launch_bounds__(256) void cvt_f32_bf16(
    const float* __restrict__ in, unsigned short* __restrict__ out, long long n8) {
    long long i = (long long)blockIdx.x * 256 + threadIdx.x;
    if (i >= n8) return;
    float4 a = ((const float4*)in)[2 * i];
    float4 b = ((const float4*)in)[2 * i + 1];
    ushort4 p0, p1;
    p0.x = f2bf(a.x); p0.y = f2bf(a.y); p0.z = f2bf(a.z); p0.w = f2bf(a.w);
    p1.x = f2bf(b.x); p1.y = f2bf(b.y); p1.z = f2bf(b.z); p1.w = f2bf(b.w);
    ((ushort4*)out)[2 * i] = p0;
    ((ushort4*)out)[2 * i + 1] = p1;
}

// ---------------- transpose + convert: f32 [R][C] -> bf16 [C][R] -----------
__global__ __launch_bounds__(256) void transpose_cvt(
    const float* __restrict__ in, unsigned short* __restrict__ out, int R, int C) {
    __shared__ unsigned short tile[32][33];
    int c0 = blockIdx.x * 32, r0 = blockIdx.y * 32;
    int cc = threadIdx.x & 31, rr = threadIdx.x >> 5;
#pragma unroll
    for (int p = 0; p < 4; ++p) {
        int r = rr + p * 8;
        tile[r][cc] = f2bf(in[(size_t)(r0 + r) * C + c0 + cc]);
    }
    __syncthreads();
#pragma unroll
    for (int p = 0; p < 4; ++p) {
        int c = rr + p * 8;
        out[(size_t)(c0 + c) * R + r0 + cc] = tile[cc][c];
    }
}

// ---------------- per-batch Cauchy-Schwarz bound: B_z = Qmax*Kmax/32 -------
__global__ __launch_bounds__(256) void bounds_kernel(
    const float* __restrict__ nrm, float* __restrict__ bounds) {
    const int z = blockIdx.x, t = threadIdx.x;
    float qm = 0.f, km = 0.f;
    for (int i = t; i < 2048; i += 256) {
        qm = fmaxf(qm, nrm[z * 2048 + i]);
        km = fmaxf(km, nrm[8192 + z * 2048 + i]);
    }
#pragma unroll
    for (int off = 32; off; off >>= 1) {
        qm = fmaxf(qm, __shfl_xor(qm, off));
        km = fmaxf(km, __shfl_xor(km, off));
    }
    __shared__ float rq[4], rk[4];
    const int lane = t & 63, wid = t >> 6;
    if (lane == 0) { rq[wid] = qm; rk[wid] = km; }
    __syncthreads();
    if (t == 0) {
        qm = fmaxf(fmaxf(rq[0], rq[1]), fmaxf(rq[2], rq[3]));
        km = fmaxf(fmaxf(rk[0], rk[1]), fmaxf(rk[2], rk[3]));
        bounds[z] = sqrtf(qm) * sqrtf(km) * 0.03125f;
    }
}

// ---------------- gemm5: 256x128 pipelined GEMM, C = A @ B^T ---------------
// 512 threads = 8 waves (4 row x 2 col), wave tile 64x64, BK=64.
// Parity LDS buffers X/Y, counted vmcnt(4), XOR-swizzled layout.
// EPI 1: bf16 = acc+bias[n]; atomicAdd per-row sum(val^2) into stat for
//        q (cols<1024) / k (1024..2047) segments.
// EPI 2: vT bf16: out[(m>>11)*1024+n][m&2047] = (acc+bias[n])*sigmoid(gate)
// EPI 5: P' bf16 = exp(acc*scale - bnd[z]); atomicAdd row sums into stat.
// EPI 6: f32 = mix[n]*(acc/l[row]) + (1-mix[n])*xres  (l read in epilogue)
template <int EPI>
__global__ __launch_bounds__(512, 1) void gemm5(
    const unsigned short* __restrict__ A, int lda, long long Abs,
    const unsigned short* __restrict__ B, int ldb, long long Bbs,
    int K,
    void* __restrict__ out, int ldo, long long Obs,
    const float* __restrict__ bias,
    const unsigned short* __restrict__ gate, int ldg,
    const float* __restrict__ xres, const float* __restrict__ mix,
    float scale, int gx,
    const float* __restrict__ bnd, float* __restrict__ stat) {
    __shared__ unsigned short lds[49152];  // X @0, Y @24576 (ushorts)
    const int tid = threadIdx.x, lane = tid & 63, wid = tid >> 6;
    const int wr = wid >> 1, wc = wid & 1;
    const int nwg = gridDim.x;
    const int bswz = ((int)blockIdx.x & 7) * (nwg >> 3) + ((int)blockIdx.x >> 3);
    const int bx = bswz % gx, by = bswz / gx;
    const int bm = by * 256, bn = bx * 128;
    const int z = blockIdx.z;
    A += (long long)z * Abs;
    B += (long long)z * Bbs;
    const int NT = K >> 6;  // even, >= 2

    const int sswz = ((tid & 7) ^ ((tid >> 3) & 7)) * 8;
    size_t agc[4], bgc[2];
#pragma unroll
    for (int c = 0; c < 4; ++c)
        agc[c] = (size_t)(bm + c * 64 + (tid >> 3)) * lda + sswz;
#pragma unroll
    for (int c = 0; c < 2; ++c)
        bgc[c] = (size_t)(bn + c * 64 + (tid >> 3)) * ldb + sswz;
    const int wl = wid * 512;

    auto stA01 = [&](int t, int buf) {
        const size_t k0 = (size_t)t << 6;
        llds16(A + agc[0] + k0, &lds[buf + wl]);
        llds16(A + agc[1] + k0, &lds[buf + 4096 + wl]);
    };
    auto stA23 = [&](int t, int buf) {
        const size_t k0 = (size_t)t << 6;
        llds16(A + agc[2] + k0, &lds[buf + 8192 + wl]);
        llds16(A + agc[3] + k0, &lds[buf + 12288 + wl]);
    };
    auto stB = [&](int t, int buf) {
        const size_t k0 = (size_t)t << 6;
        llds16(B + bgc[0] + k0, &lds[buf + 16384 + wl]);
        llds16(B + bgc[1] + k0, &lds[buf + 20480 + wl]);
    };

    const int l15 = lane & 15, g4 = lane >> 4, l7 = lane & 7;
    const int x0 = (g4 ^ l7) * 8, x1 = ((4 + g4) ^ l7) * 8;
    const int ab = (wr * 64 + l15) * 64;
    const int bbv = 16384 + (wc * 64 + l15) * 64;
    constexpr int X = 0, Y = 24576;

    f32x4 acc[4][4] = {};

    // prologue: ONLY staging VMEM ops may issue here (vmcnt ledger).
    stB(0, X); stA01(0, X); stA23(0, X); stB(1, Y);
    VM4;
    BAR; SCB;

    int t = 0;
    while (true) {
        const bool last = (t + 2) >= NT;
        bf16x8 bf[4][2], af[2][2];
        // ---- F0
#pragma unroll
        for (int j = 0; j < 4; ++j) {
            bf[j][0] = *(const bf16x8*)&lds[X + bbv + j * 1024 + x0];
            bf[j][1] = *(const bf16x8*)&lds[X + bbv + j * 1024 + x1];
        }
#pragma unroll
        for (int i = 0; i < 2; ++i) {
            af[i][0] = *(const bf16x8*)&lds[X + ab + i * 1024 + x0];
            af[i][1] = *(const bf16x8*)&lds[X + ab + i * 1024 + x1];
        }
        stA01(t + 1, Y);
        LGKM0; SCB;
        __builtin_amdgcn_s_setprio(1);
#pragma unroll
        for (int s = 0; s < 2; ++s)
#pragma unroll
            for (int i = 0; i < 2; ++i)
#pragma unroll
                for (int j = 0; j < 4; ++j)
                    acc[i][j] = MF(af[i][s], bf[j][s], acc[i][j]);
        __builtin_amdgcn_s_setprio(0);
        VM4;
        BAR; SCB;
        // ---- F1
#pragma unroll
        for (int i = 0; i < 2; ++i) {
            af[i][0] = *(const bf16x8*)&lds[X + ab + (2 + i) * 1024 + x0];
            af[i][1] = *(const bf16x8*)&lds[X + ab + (2 + i) * 1024 + x1];
        }
        stA23(t + 1, Y);
        if (!last) stB(t + 2, X);
        LGKM0; SCB;
        __builtin_amdgcn_s_setprio(1);
#pragma unroll
        for (int s = 0; s < 2; ++s)
#pragma unroll
            for (int i = 0; i < 2; ++i)
#pragma unroll
                for (int j = 0; j < 4; ++j)
                    acc[2 + i][j] = MF(af[i][s], bf[j][s], acc[2 + i][j]);
        __builtin_amdgcn_s_setprio(0);
        if (last) { VM2; } else { VM4; }
        BAR; SCB;
        // ---- F2
#pragma unroll
        for (int j = 0; j < 4; ++j) {
            bf[j][0] = *(const bf16x8*)&lds[Y + bbv + j * 1024 + x0];
            bf[j][1] = *(const bf16x8*)&lds[Y + bbv + j * 1024 + x1];
        }
#pragma unroll
        for (int i = 0; i < 2; ++i) {
            af[i][0] = *(const bf16x8*)&lds[Y + ab + i * 1024 + x0];
            af[i][1] = *(const bf16x8*)&lds[Y + ab + i * 1024 + x1];
        }
        if (!last) stA01(t + 2, X);
        LGKM0; SCB;
        __builtin_amdgcn_s_setprio(1);
#pragma unroll
        for (int s = 0; s < 2; ++s)
#pragma unroll
            for (int i = 0; i < 2; ++i)
#pragma unroll
                for (int j = 0; j < 4; ++j)
                    acc[i][j] = MF(af[i][s], bf[j][s], acc[i][j]);
        __builtin_amdgcn_s_setprio(0);
        if (last) { VM0; } else { VM4; }
        BAR; SCB;
        // ---- F3
#pragma unroll
        for (int i = 0; i < 2; ++i) {
            af[i][0] = *(const bf16x8*)&lds[Y + ab + (2 + i) * 1024 + x0];
            af[i][1] = *(const bf16x8*)&lds[Y + ab + (2 + i) * 1024 + x1];
        }
        if (!last) { stA23(t + 2, X); stB(t + 3, Y); }
        LGKM0; SCB;
        __builtin_amdgcn_s_setprio(1);
#pragma unroll
        for (int s = 0; s < 2; ++s)
#pragma unroll
            for (int i = 0; i < 2; ++i)
#pragma unroll
                for (int j = 0; j < 4; ++j)
                    acc[2 + i][j] = MF(af[i][s], bf[j][s], acc[2 + i][j]);
        __builtin_amdgcn_s_setprio(0);
        if (last) break;
        VM4;
        BAR; SCB;
        t += 2;
    }

    // --- epilogue (all global reads here are AFTER the final "memory" asm,
    // so they cannot be hoisted into the counted-vmcnt region)
    const int row0 = bm + wr * 64, col0 = bn + wc * 64;
    if constexpr (EPI == 1) {
        unsigned short* o = (unsigned short*)out;
        const int seg = col0 >> 10;  // 0=q, 1=k, 2=g
#pragma unroll
        for (int i = 0; i < 4; ++i) {
            const int mb = row0 + i * 16 + g4 * 4;
            float ssq[4] = {0.f, 0.f, 0.f, 0.f};
#pragma unroll
            for (int j = 0; j < 4; ++j) {
                const int n = col0 + j * 16 + l15;
                const float bs = bias[n];
#pragma unroll
                for (int q = 0; q < 4; ++q) {
                    float val = acc[i][j][q] + bs;
                    o[(size_t)(mb + q) * ldo + n] = f2bf(val);
                    ssq[q] += val * val;
                }
            }
            if (seg < 2) {
#pragma unroll
                for (int q = 0; q < 4; ++q) {
                    float s = ssq[q];
                    s += __shfl_xor(s, 1); s += __shfl_xor(s, 2);
                    s += __shfl_xor(s, 4); s += __shfl_xor(s, 8);
                    if (l15 == 0) atomicAdd(&stat[seg * 8192 + mb + q], s);
                }
            }
        }
    } else if constexpr (EPI == 2) {
        unsigned short* o = (unsigned short*)out;
#pragma unroll
        for (int i = 0; i < 4; ++i) {
            const int mb = row0 + i * 16 + g4 * 4;
#pragma unroll
            for (int j = 0; j < 4; ++j) {
                const int n = col0 + j * 16 + l15;
                const float bs = bias[n];
                ushort4 pk;
                unsigned short* pku = (unsigned short*)&pk;
#pragma unroll
                for (int q = 0; q < 4; ++q) {
                    int m = mb + q;
                    float g = bf2f(gate[(size_t)m * ldg + n]);
                    pku[q] = f2bf((acc[i][j][q] + bs) / (1.f + __expf(-g)));
                }
                size_t oi = ((size_t)(mb >> 11) * 1024 + n) * 2048 + (mb & 2047);
                *(ushort4*)(o + oi) = pk;
            }
        }
    } else if constexpr (EPI == 5) {
        unsigned short* o = (unsigned short*)out + (size_t)z * Obs;
        const float Bz = bnd[z];
#pragma unroll
        for (int i = 0; i < 4; ++i) {
            const int mb = row0 + i * 16 + g4 * 4;
            float rs[4] = {0.f, 0.f, 0.f, 0.f};
#pragma unroll
            for (int j = 0; j < 4; ++j) {
                const int n = col0 + j * 16 + l15;
#pragma unroll
                for (int q = 0; q < 4; ++q) {
                    float p = __expf(acc[i][j][q] * scale - Bz);
                    o[(size_t)(mb + q) * ldo + n] = f2bf(p);
                    rs[q] += p;
                }
            }
#pragma unroll
            for (int q = 0; q < 4; ++q) {
                float s = rs[q];
                s += __shfl_xor(s, 1); s += __shfl_xor(s, 2);
                s += __shfl_xor(s, 4); s += __shfl_xor(s, 8);
                if (l15 == 0) atomicAdd(&stat[(size_t)z * 2048 + mb + q], s);
            }
        }
    } else {  // EPI == 6
        float* o = (float*)out + (size_t)z * Obs;
        const float* xr = xres + (size_t)z * Obs;
        const float* ls = bnd + (size_t)z * 2048;  // softmax row sums
#pragma unroll
        for (int i = 0; i < 4; ++i) {
            const int mb = row0 + i * 16 + g4 * 4;
            float invl[4];
#pragma unroll
            for (int q = 0; q < 4; ++q) invl[q] = 1.f / ls[mb + q];
#pragma unroll
            for (int j = 0; j < 4; ++j) {
                const int n = col0 + j * 16 + l15;
                const float mw = mix[n];
#pragma unroll
                for (int q = 0; q < 4; ++q)
                    o[(size_t)(mb + q) * ldo + n] =
                        mw * (acc[i][j][q] * invl[q]) +
                        (1.f - mw) * xr[(size_t)(mb + q) * ldo + n];
            }
        }
    }
}

// ---------------- gemmk: 128x128 ring-3 GEMM (GEMM1 only) ------------------
template <int EPI>
__global__ __launch_bounds__(256, 3) void gemmk(
    const unsigned short* __restrict__ A, int lda,
    const unsigned short* __restrict__ B, int ldb,
    int K, void* __restrict__ out, int ldo,
    const float* __restrict__ bias, int gx) {
    __shared__ unsigned short lds[24576];
    const int tid = threadIdx.x, lane = tid & 63, wid = tid >> 6;
    const int nwg = gridDim.x;
    const int bswz = ((int)blockIdx.x & 7) * (nwg >> 3) + ((int)blockIdx.x >> 3);
    const int bx = bswz % gx, by = bswz / gx;
    const int bm = by * 128, bn = bx * 128;
    const int NT = K >> 5;

    const int srow = tid >> 2;
    const int sswz = ((tid & 3) ^ ((tid >> 3) & 3)) * 8;
    size_t ag[2], bg[2];
    ag[0] = (size_t)(bm + srow) * lda + sswz;
    ag[1] = (size_t)(bm + 64 + srow) * lda + sswz;
    bg[0] = (size_t)(bn + srow) * ldb + sswz;
    bg[1] = (size_t)(bn + 64 + srow) * ldb + sswz;
    const int wl = wid * 512;

    auto stage = [&](int t, int bb) {
        const size_t k0 = (size_t)t << 5;
        llds16(A + ag[0] + k0, &lds[bb + wl]);
        llds16(A + ag[1] + k0, &lds[bb + 2048 + wl]);
        llds16(B + bg[0] + k0, &lds[bb + 4096 + wl]);
        llds16(B + bg[1] + k0, &lds[bb + 6144 + wl]);
    };

    const int wr = wid >> 1, wc = wid & 1;
    const int l15 = lane & 15, g4 = lane >> 4;
    const int fswz = (g4 ^ ((l15 >> 1) & 3)) * 8;
    const int aoff = (wr * 64 + l15) * 32 + fswz;
    const int boff = 4096 + (wc * 64 + l15) * 32 + fswz;

    f32x4 acc[4][4] = {};
    stage(0, 0);
    stage(1, 8192);
    VM4; BAR;

    int bb = 0;
    for (int t = 0; t < NT; ++t) {
        const bool st = (t + 2) < NT;
        if (st) {
            const int tgt = (bb >= 8192) ? bb - 8192 : bb + 16384;
            stage(t + 2, tgt);
        }
        SCB;
        bf16x8 af[4], bf[4];
#pragma unroll
        for (int i = 0; i < 4; ++i) {
            af[i] = *(const bf16x8*)&lds[bb + aoff + i * 512];
            bf[i] = *(const bf16x8*)&lds[bb + boff + i * 512];
        }
#pragma unroll
        for (int i = 0; i < 4; ++i)
#pragma unroll
            for (int j = 0; j < 4; ++j)
                acc[i][j] = MF(af[i], bf[j], acc[i][j]);
        LGKM0;
        if (st) { VM4; } else { VM0; }
        BAR;
        bb = (bb == 16384) ? 0 : bb + 8192;
    }

    const int row0 = bm + wr * 64, col0 = bn + wc * 64;
#pragma unroll
    for (int i = 0; i < 4; ++i) {
#pragma unroll
        for (int j = 0; j < 4; ++j) {
            const int n = col0 + j * 16 + l15;
            const int mb = row0 + i * 16 + g4 * 4;
            f32x4 v = acc[i][j];
            float bs = bias[n];
            unsigned short* o = (unsigned short*)out;
#pragma unroll
            for (int q = 0; q < 4; ++q) {
                float val = v[q] + bs;
                if constexpr (EPI == 0) val = val / (1.f + __expf(-val));
                o[(size_t)(mb + q) * ldo + n] = f2bf(val);
            }
        }
    }
}

// ---------------- in-place RMSNorm over rows of D=1024 f32 ----------------
__global__ __launch_bounds__(256) void rmsnorm_inplace(
    float* __restrict__ io, const float* __restrict__ w) {
    const int D = 1024;
    float* r = io + (size_t)blockIdx.x * D;
    const int t = threadIdx.x, lane = t & 63, wid = t >> 6;
    float4 v = ((const float4*)r)[t];
    float ss = v.x * v.x + v.y * v.y + v.z * v.z + v.w * v.w;
#pragma unroll
    for (int off = 32; off; off >>= 1) ss += __shfl_xor(ss, off);
    __shared__ float red[4];
    if (lane == 0) red[wid] = ss;
    __syncthreads();
    ss = red[0] + red[1] + red[2] + red[3];
    float sc = rsqrtf(ss / (float)D + 1e-6f);
    float4 wv = ((const float4*)w)[t];
    v.x *= sc * wv.x; v.y *= sc * wv.y; v.z *= sc * wv.z; v.w *= sc * wv.w;
    ((float4*)r)[t] = v;
}

// ---------------------------------------------------------------------------
extern "C" void kernel_launch(void* const* d_in, const int* in_sizes, int n_in,
                              void* d_out, int out_size, void* d_ws, size_t ws_size,
                              hipStream_t stream) {
    const float* x = (const float*)d_in[0];
    const float* W1 = (const float*)d_in[1];
    const float* b1 = (const float*)d_in[2];
    const float* W2 = (const float*)d_in[3];
    const float* b2 = (const float*)d_in[4];
    const float* Wv = (const float*)d_in[5];
    const float* bv = (const float*)d_in[6];
    const float* mixw = (const float*)d_in[7];
    const float* normw = (const float*)d_in[8];
    float* out = (float*)d_out;

    const int L = 2048, D = 1024, INNER = 1536, BN4 = 4;
    const int M = BN4 * L;  // 8192

    // workspace carve
    char* w = (char*)d_ws;
    auto carve = [&](size_t bytes) {
        void* p = (void*)w;
        w += (bytes + 255) & ~(size_t)255;
        return p;
    };
    unsigned short* xbf = (unsigned short*)carve((size_t)M * D * 2);
    unsigned short* w1t = (unsigned short*)carve((size_t)INNER * D * 2);
    unsigned short* w2t = (unsigned short*)carve((size_t)3 * D * INNER * 2);
    unsigned short* wvt = (unsigned short*)carve((size_t)D * D * 2);
    unsigned short* h = (unsigned short*)carve((size_t)M * INNER * 2);
    unsigned short* qkg = (unsigned short*)carve((size_t)M * 3 * D * 2);
    unsigned short* vt = (unsigned short*)carve((size_t)BN4 * D * L * 2);
    unsigned short* pbuf = (unsigned short*)carve((size_t)BN4 * L * L * 2);
    float* norm2 = (float*)carve((size_t)2 * M * 4);   // q/k row norm^2
    float* lsum = (float*)carve((size_t)M * 4);        // softmax row sums
    float* bounds = (float*)carve((size_t)BN4 * 4);    // per-batch bound

    // 0) zero the atomic accumulators (norm2 + lsum are contiguous)
    zero_f32<<<(3 * M) / 256, 256, 0, stream>>>(norm2, 3 * M);
    // 1) x -> bf16
    cvt_f32_bf16<<<(M * D) / 2048, 256, 0, stream>>>(x, xbf, (long long)M * D / 8);
    // 2-4) weights -> bf16, transposed to [N][K]
    transpose_cvt<<<dim3(INNER / 32, D / 32), 256, 0, stream>>>(W1, w1t, D, INNER);
    transpose_cvt<<<dim3(3 * D / 32, INNER / 32), 256, 0, stream>>>(W2, w2t, INNER, 3 * D);
    transpose_cvt<<<dim3(D / 32, D / 32), 256, 0, stream>>>(Wv, wvt, D, D);
    // 5) h = silu(x @ W1 + b1)     [M][INNER] bf16   (768 blocks, 3/CU)
    gemmk<0><<<dim3(768, 1, 1), 256, 0, stream>>>(xbf, D, w1t, D, D, h, INNER,
                                                  b1, 12);
    // 6) qkg = h @ W2 + b2         [M][3D] bf16; + q/k row-norm^2 atomics
    gemm5<1><<<dim3(768, 1, 1), 512, 0, stream>>>(
        h, INNER, 0, w2t, INNER, 0, INNER, qkg, 3 * D, 0, b2, nullptr, 0,
        nullptr, nullptr, 1.f, 24, nullptr, norm2);
    // 6b) per-batch Cauchy-Schwarz bound B_z
    bounds_kernel<<<BN4, 256, 0, stream>>>(norm2, bounds);
    // 7) vT = ((x @ Wv + bv)*sigmoid(g))^T  [B][D][L] bf16  (256 blocks)
    gemm5<2><<<dim3(256, 1, 1), 512, 0, stream>>>(
        xbf, D, 0, wvt, D, 0, D, vt, L, 0, bv, qkg + 2 * D, 3 * D, nullptr,
        nullptr, 1.f, 8, nullptr, nullptr);
    // 8) P' = exp(q@k^T/32 - B_z) bf16 [B][L][L]; row sums -> lsum (atomics)
    gemm5<5><<<dim3(128, 1, BN4), 512, 0, stream>>>(
        qkg, 3 * D, (long long)L * 3 * D, qkg + D, 3 * D, (long long)L * 3 * D,
        D, pbuf, L, (long long)L * L, nullptr, nullptr, 0, nullptr, nullptr,
        0.03125f, 16, bounds, lsum);
    // 9) out = mix * ((P' @ vT^T)/l) + (1-mix) * x  [B][L][D] f32 (256 blocks)
    gemm5<6><<<dim3(64, 1, BN4), 512, 0, stream>>>(
        pbuf, L, (long long)L * L, vt, L, (long long)D * L, L, out, D,
        (long long)L * D, nullptr, nullptr, 0, x, mixw, 1.f, 8, lsum, nullptr);
    // 10) in-place rmsnorm
    rmsnorm_inplace<<<M, 256, 0, stream>>>(out, normw);
}

// Round 8
// 274.244 us; speedup vs baseline: 1.1832x; 1.0293x over previous
//
#include <hip/hip_runtime.h>
#include <hip/hip_bf16.h>
#include <stdint.h>

// ---------------------------------------------------------------------------
// SelectiveMixing: x->W1->silu->W2->(q,k,g); v=(x@Wv+bv)*sig(g);
// attn=softmax(qk^T/sqrt(D)); out=rmsnorm(mix*attn@v + (1-mix)*x)
// B=4, L=2048, D=1024, INNER=1536. All matmuls bf16 MFMA, f32 accum.
// Softmax fused WITHOUT a max pass: P' = exp(min(s,80)) bf16 (floating-point
// keeps relative precision at any magnitude; clamp guarantees no f32
// overflow); f32 row sums l via atomics; PV epilogue applies 1/l and writes
// gi bf16; one fused mix+rmsnorm pass produces the f32 output.
// RULE: inside gemm5's counted-vmcnt region NO other VMEM op may issue.
// ---------------------------------------------------------------------------

typedef __bf16 bf16x8 __attribute__((ext_vector_type(8)));
typedef float f32x4 __attribute__((ext_vector_type(4)));

#define VM4 asm volatile("s_waitcnt vmcnt(4)" ::: "memory")
#define VM2 asm volatile("s_waitcnt vmcnt(2)" ::: "memory")
#define VM0 asm volatile("s_waitcnt vmcnt(0)" ::: "memory")
#define LGKM0 asm volatile("s_waitcnt lgkmcnt(0)" ::: "memory")
#define BAR __builtin_amdgcn_s_barrier()
#define SCB __builtin_amdgcn_sched_barrier(0)

__device__ __forceinline__ unsigned short f2bf(float f) {
    unsigned int u = __float_as_uint(f);
    u += 0x7fffu + ((u >> 16) & 1u);
    return (unsigned short)(u >> 16);
}
__device__ __forceinline__ float bf2f(unsigned short s) {
    return __uint_as_float(((unsigned int)s) << 16);
}
__device__ __forceinline__ void llds16(const void* g, void* l) {
    __builtin_amdgcn_global_load_lds(
        (const __attribute__((address_space(1))) void*)g,
        (__attribute__((address_space(3))) void*)l, 16, 0, 0);
}
__device__ __forceinline__ f32x4 MF(bf16x8 a, bf16x8 b, f32x4 c) {
    return __builtin_amdgcn_mfma_f32_16x16x32_bf16(a, b, c, 0, 0, 0);
}

// ---------------- zero fill ------------------------------------------------
__global__ __launch_bounds__(256) void zero_f32(float* __restrict__ p, int n) {
    int i = blockIdx.x * 256 + threadIdx.x;
    if (i < n) p[i] = 0.f;
}

// ---------------- elementwise: f32 -> bf16 (8 elems/thread) ----------------
__global__ __launch_bounds__(256) void cvt_f32_bf16(
    const float* __restrict__ in, unsigned short* __restrict__ out, long long n8) {
    long long i = (long long)blockIdx.x * 256 + threadIdx.x;
    if (i >= n8) return;
    float4 a = ((const float4*)in)[2 * i];
    float4 b = ((const float4*)in)[2 * i + 1];
    ushort4 p0, p1;
    p0.x = f2bf(a.x); p0.y = f2bf(a.y); p0.z = f2bf(a.z); p0.w = f2bf(a.w);
    p1.x = f2bf(b.x); p1.y = f2bf(b.y); p1.z = f2bf(b.z); p1.w = f2bf(b.w);
    ((ushort4*)out)[2 * i] = p0;
    ((ushort4*)out)[2 * i + 1] = p1;
}

// ---------------- transpose + convert: f32 [R][C] -> bf16 [C][R] -----------
__global__ __launch_bounds__(256) void transpose_cvt(
    const float* __restrict__ in, unsigned short* __restrict__ out, int R, int C) {
    __shared__ unsigned short tile[32][33];
    int c0 = blockIdx.x * 32, r0 = blockIdx.y * 32;
    int cc = threadIdx.x & 31, rr = threadIdx.x >> 5;
#pragma unroll
    for (int p = 0; p < 4; ++p) {
        int r = rr + p * 8;
        tile[r][cc] = f2bf(in[(size_t)(r0 + r) * C + c0 + cc]);
    }
    __syncthreads();
#pragma unroll
    for (int p = 0; p < 4; ++p) {
        int c = rr + p * 8;
        out[(size_t)(c0 + c) * R + r0 + cc] = tile[cc][c];
    }
}

// ---------------- gemm5: 256x128 pipelined GEMM, C = A @ B^T ---------------
// 512 threads = 8 waves (4 row x 2 col), wave tile 64x64, BK=64.
// Parity LDS buffers X/Y, counted vmcnt(4), XOR-swizzled layout.
// EPI 1: bf16 = acc+bias[n]
// EPI 2: vT bf16: out[(m>>11)*1024+n][m&2047] = (acc+bias[n])*sigmoid(gate)
// EPI 5: P' bf16 = exp(min(acc*scale,80)); atomicAdd row sums into stat.
// EPI 6: gi bf16 = acc / l[row]   (l read in epilogue via bnd)
template <int EPI>
__global__ __launch_bounds__(512, 1) void gemm5(
    const unsigned short* __restrict__ A, int lda, long long Abs,
    const unsigned short* __restrict__ B, int ldb, long long Bbs,
    int K,
    void* __restrict__ out, int ldo, long long Obs,
    const float* __restrict__ bias,
    const unsigned short* __restrict__ gate, int ldg,
    float scale, int gx,
    const float* __restrict__ bnd, float* __restrict__ stat) {
    __shared__ unsigned short lds[49152];  // X @0, Y @24576 (ushorts)
    const int tid = threadIdx.x, lane = tid & 63, wid = tid >> 6;
    const int wr = wid >> 1, wc = wid & 1;
    const int nwg = gridDim.x;
    const int bswz = ((int)blockIdx.x & 7) * (nwg >> 3) + ((int)blockIdx.x >> 3);
    const int bx = bswz % gx, by = bswz / gx;
    const int bm = by * 256, bn = bx * 128;
    const int z = blockIdx.z;
    A += (long long)z * Abs;
    B += (long long)z * Bbs;
    const int NT = K >> 6;  // even, >= 2

    const int sswz = ((tid & 7) ^ ((tid >> 3) & 7)) * 8;
    size_t agc[4], bgc[2];
#pragma unroll
    for (int c = 0; c < 4; ++c)
        agc[c] = (size_t)(bm + c * 64 + (tid >> 3)) * lda + sswz;
#pragma unroll
    for (int c = 0; c < 2; ++c)
        bgc[c] = (size_t)(bn + c * 64 + (tid >> 3)) * ldb + sswz;
    const int wl = wid * 512;

    auto stA01 = [&](int t, int buf) {
        const size_t k0 = (size_t)t << 6;
        llds16(A + agc[0] + k0, &lds[buf + wl]);
        llds16(A + agc[1] + k0, &lds[buf + 4096 + wl]);
    };
    auto stA23 = [&](int t, int buf) {
        const size_t k0 = (size_t)t << 6;
        llds16(A + agc[2] + k0, &lds[buf + 8192 + wl]);
        llds16(A + agc[3] + k0, &lds[buf + 12288 + wl]);
    };
    auto stB = [&](int t, int buf) {
        const size_t k0 = (size_t)t << 6;
        llds16(B + bgc[0] + k0, &lds[buf + 16384 + wl]);
        llds16(B + bgc[1] + k0, &lds[buf + 20480 + wl]);
    };

    const int l15 = lane & 15, g4 = lane >> 4, l7 = lane & 7;
    const int x0 = (g4 ^ l7) * 8, x1 = ((4 + g4) ^ l7) * 8;
    const int ab = (wr * 64 + l15) * 64;
    const int bbv = 16384 + (wc * 64 + l15) * 64;
    constexpr int X = 0, Y = 24576;

    f32x4 acc[4][4] = {};

    // prologue: ONLY staging VMEM ops may issue here (vmcnt ledger).
    stB(0, X); stA01(0, X); stA23(0, X); stB(1, Y);
    VM4;
    BAR; SCB;

    int t = 0;
    while (true) {
        const bool last = (t + 2) >= NT;
        bf16x8 bf[4][2], af[2][2];
        // ---- F0
#pragma unroll
        for (int j = 0; j < 4; ++j) {
            bf[j][0] = *(const bf16x8*)&lds[X + bbv + j * 1024 + x0];
            bf[j][1] = *(const bf16x8*)&lds[X + bbv + j * 1024 + x1];
        }
#pragma unroll
        for (int i = 0; i < 2; ++i) {
            af[i][0] = *(const bf16x8*)&lds[X + ab + i * 1024 + x0];
            af[i][1] = *(const bf16x8*)&lds[X + ab + i * 1024 + x1];
        }
        stA01(t + 1, Y);
        LGKM0; SCB;
        __builtin_amdgcn_s_setprio(1);
#pragma unroll
        for (int s = 0; s < 2; ++s)
#pragma unroll
            for (int i = 0; i < 2; ++i)
#pragma unroll
                for (int j = 0; j < 4; ++j)
                    acc[i][j] = MF(af[i][s], bf[j][s], acc[i][j]);
        __builtin_amdgcn_s_setprio(0);
        VM4;
        BAR; SCB;
        // ---- F1
#pragma unroll
        for (int i = 0; i < 2; ++i) {
            af[i][0] = *(const bf16x8*)&lds[X + ab + (2 + i) * 1024 + x0];
            af[i][1] = *(const bf16x8*)&lds[X + ab + (2 + i) * 1024 + x1];
        }
        stA23(t + 1, Y);
        if (!last) stB(t + 2, X);
        LGKM0; SCB;
        __builtin_amdgcn_s_setprio(1);
#pragma unroll
        for (int s = 0; s < 2; ++s)
#pragma unroll
            for (int i = 0; i < 2; ++i)
#pragma unroll
                for (int j = 0; j < 4; ++j)
                    acc[2 + i][j] = MF(af[i][s], bf[j][s], acc[2 + i][j]);
        __builtin_amdgcn_s_setprio(0);
        if (last) { VM2; } else { VM4; }
        BAR; SCB;
        // ---- F2
#pragma unroll
        for (int j = 0; j < 4; ++j) {
            bf[j][0] = *(const bf16x8*)&lds[Y + bbv + j * 1024 + x0];
            bf[j][1] = *(const bf16x8*)&lds[Y + bbv + j * 1024 + x1];
        }
#pragma unroll
        for (int i = 0; i < 2; ++i) {
            af[i][0] = *(const bf16x8*)&lds[Y + ab + i * 1024 + x0];
            af[i][1] = *(const bf16x8*)&lds[Y + ab + i * 1024 + x1];
        }
        if (!last) stA01(t + 2, X);
        LGKM0; SCB;
        __builtin_amdgcn_s_setprio(1);
#pragma unroll
        for (int s = 0; s < 2; ++s)
#pragma unroll
            for (int i = 0; i < 2; ++i)
#pragma unroll
                for (int j = 0; j < 4; ++j)
                    acc[i][j] = MF(af[i][s], bf[j][s], acc[i][j]);
        __builtin_amdgcn_s_setprio(0);
        if (last) { VM0; } else { VM4; }
        BAR; SCB;
        // ---- F3
#pragma unroll
        for (int i = 0; i < 2; ++i) {
            af[i][0] = *(const bf16x8*)&lds[Y + ab + (2 + i) * 1024 + x0];
            af[i][1] = *(const bf16x8*)&lds[Y + ab + (2 + i) * 1024 + x1];
        }
        if (!last) { stA23(t + 2, X); stB(t + 3, Y); }
        LGKM0; SCB;
        __builtin_amdgcn_s_setprio(1);
#pragma unroll
        for (int s = 0; s < 2; ++s)
#pragma unroll
            for (int i = 0; i < 2; ++i)
#pragma unroll
                for (int j = 0; j < 4; ++j)
                    acc[2 + i][j] = MF(af[i][s], bf[j][s], acc[2 + i][j]);
        __builtin_amdgcn_s_setprio(0);
        if (last) break;
        VM4;
        BAR; SCB;
        t += 2;
    }

    // --- epilogue (all global reads AFTER the final "memory" asm)
    const int row0 = bm + wr * 64, col0 = bn + wc * 64;
    if constexpr (EPI == 1) {
        unsigned short* o = (unsigned short*)out;
#pragma unroll
        for (int i = 0; i < 4; ++i) {
            const int mb = row0 + i * 16 + g4 * 4;
#pragma unroll
            for (int j = 0; j < 4; ++j) {
                const int n = col0 + j * 16 + l15;
                const float bs = bias[n];
#pragma unroll
                for (int q = 0; q < 4; ++q)
                    o[(size_t)(mb + q) * ldo + n] = f2bf(acc[i][j][q] + bs);
            }
        }
    } else if constexpr (EPI == 2) {
        unsigned short* o = (unsigned short*)out;
#pragma unroll
        for (int i = 0; i < 4; ++i) {
            const int mb = row0 + i * 16 + g4 * 4;
#pragma unroll
            for (int j = 0; j < 4; ++j) {
                const int n = col0 + j * 16 + l15;
                const float bs = bias[n];
                ushort4 pk;
                unsigned short* pku = (unsigned short*)&pk;
#pragma unroll
                for (int q = 0; q < 4; ++q) {
                    int m = mb + q;
                    float g = bf2f(gate[(size_t)m * ldg + n]);
                    pku[q] = f2bf((acc[i][j][q] + bs) / (1.f + __expf(-g)));
                }
                size_t oi = ((size_t)(mb >> 11) * 1024 + n) * 2048 + (mb & 2047);
                *(ushort4*)(o + oi) = pk;
            }
        }
    } else if constexpr (EPI == 5) {
        unsigned short* o = (unsigned short*)out + (size_t)z * Obs;
#pragma unroll
        for (int i = 0; i < 4; ++i) {
            const int mb = row0 + i * 16 + g4 * 4;
            float rs[4] = {0.f, 0.f, 0.f, 0.f};
#pragma unroll
            for (int j = 0; j < 4; ++j) {
                const int n = col0 + j * 16 + l15;
#pragma unroll
                for (int q = 0; q < 4; ++q) {
                    float p = __expf(fminf(acc[i][j][q] * scale, 80.f));
                    o[(size_t)(mb + q) * ldo + n] = f2bf(p);
                    rs[q] += p;
                }
            }
#pragma unroll
            for (int q = 0; q < 4; ++q) {
                float s = rs[q];
                s += __shfl_xor(s, 1); s += __shfl_xor(s, 2);
                s += __shfl_xor(s, 4); s += __shfl_xor(s, 8);
                if (l15 == 0) atomicAdd(&stat[(size_t)z * 2048 + mb + q], s);
            }
        }
    } else {  // EPI == 6: gi bf16 = acc / l[row]
        unsigned short* o = (unsigned short*)out + (size_t)z * Obs;
        const float* ls = bnd + (size_t)z * 2048;
#pragma unroll
        for (int i = 0; i < 4; ++i) {
            const int mb = row0 + i * 16 + g4 * 4;
            float invl[4];
#pragma unroll
            for (int q = 0; q < 4; ++q) invl[q] = 1.f / ls[mb + q];
#pragma unroll
            for (int j = 0; j < 4; ++j) {
                const int n = col0 + j * 16 + l15;
#pragma unroll
                for (int q = 0; q < 4; ++q)
                    o[(size_t)(mb + q) * ldo + n] = f2bf(acc[i][j][q] * invl[q]);
            }
        }
    }
}

// ---------------- gemmk: 128x128 ring-3 GEMM (GEMM1 only) ------------------
template <int EPI>
__global__ __launch_bounds__(256, 3) void gemmk(
    const unsigned short* __restrict__ A, int lda,
    const unsigned short* __restrict__ B, int ldb,
    int K, void* __restrict__ out, int ldo,
    const float* __restrict__ bias, int gx) {
    __shared__ unsigned short lds[24576];
    const int tid = threadIdx.x, lane = tid & 63, wid = tid >> 6;
    const int nwg = gridDim.x;
    const int bswz = ((int)blockIdx.x & 7) * (nwg >> 3) + ((int)blockIdx.x >> 3);
    const int bx = bswz % gx, by = bswz / gx;
    const int bm = by * 128, bn = bx * 128;
    const int NT = K >> 5;

    const int srow = tid >> 2;
    const int sswz = ((tid & 3) ^ ((tid >> 3) & 3)) * 8;
    size_t ag[2], bg[2];
    ag[0] = (size_t)(bm + srow) * lda + sswz;
    ag[1] = (size_t)(bm + 64 + srow) * lda + sswz;
    bg[0] = (size_t)(bn + srow) * ldb + sswz;
    bg[1] = (size_t)(bn + 64 + srow) * ldb + sswz;
    const int wl = wid * 512;

    auto stage = [&](int t, int bb) {
        const size_t k0 = (size_t)t << 5;
        llds16(A + ag[0] + k0, &lds[bb + wl]);
        llds16(A + ag[1] + k0, &lds[bb + 2048 + wl]);
        llds16(B + bg[0] + k0, &lds[bb + 4096 + wl]);
        llds16(B + bg[1] + k0, &lds[bb + 6144 + wl]);
    };

    const int wr = wid >> 1, wc = wid & 1;
    const int l15 = lane & 15, g4 = lane >> 4;
    const int fswz = (g4 ^ ((l15 >> 1) & 3)) * 8;
    const int aoff = (wr * 64 + l15) * 32 + fswz;
    const int boff = 4096 + (wc * 64 + l15) * 32 + fswz;

    f32x4 acc[4][4] = {};
    stage(0, 0);
    stage(1, 8192);
    VM4; BAR;

    int bb = 0;
    for (int t = 0; t < NT; ++t) {
        const bool st = (t + 2) < NT;
        if (st) {
            const int tgt = (bb >= 8192) ? bb - 8192 : bb + 16384;
            stage(t + 2, tgt);
        }
        SCB;
        bf16x8 af[4], bf[4];
#pragma unroll
        for (int i = 0; i < 4; ++i) {
            af[i] = *(const bf16x8*)&lds[bb + aoff + i * 512];
            bf[i] = *(const bf16x8*)&lds[bb + boff + i * 512];
        }
#pragma unroll
        for (int i = 0; i < 4; ++i)
#pragma unroll
            for (int j = 0; j < 4; ++j)
                acc[i][j] = MF(af[i], bf[j], acc[i][j]);
        LGKM0;
        if (st) { VM4; } else { VM0; }
        BAR;
        bb = (bb == 16384) ? 0 : bb + 8192;
    }

    const int row0 = bm + wr * 64, col0 = bn + wc * 64;
#pragma unroll
    for (int i = 0; i < 4; ++i) {
#pragma unroll
        for (int j = 0; j < 4; ++j) {
            const int n = col0 + j * 16 + l15;
            const int mb = row0 + i * 16 + g4 * 4;
            f32x4 v = acc[i][j];
            float bs = bias[n];
            unsigned short* o = (unsigned short*)out;
#pragma unroll
            for (int q = 0; q < 4; ++q) {
                float val = v[q] + bs;
                if constexpr (EPI == 0) val = val / (1.f + __expf(-val));
                o[(size_t)(mb + q) * ldo + n] = f2bf(val);
            }
        }
    }
}

// ---------------- fused mix + RMSNorm: out f32 [row][1024] ----------------
// v = mix*gi + (1-mix)*x ; out = v / rms(v) * normw
__global__ __launch_bounds__(256) void mix_rmsnorm(
    const unsigned short* __restrict__ gi, const float* __restrict__ x,
    const float* __restrict__ mixw, const float* __restrict__ normw,
    float* __restrict__ out) {
    const int D = 1024;
    const size_t base = (size_t)blockIdx.x * D;
    const int t = threadIdx.x, lane = t & 63, wid = t >> 6;
    ushort4 g4 = ((const ushort4*)(gi + base))[t];
    float4 xv = ((const float4*)(x + base))[t];
    float4 mw = ((const float4*)mixw)[t];
    float4 v;
    v.x = mw.x * bf2f(g4.x) + (1.f - mw.x) * xv.x;
    v.y = mw.y * bf2f(g4.y) + (1.f - mw.y) * xv.y;
    v.z = mw.z * bf2f(g4.z) + (1.f - mw.z) * xv.z;
    v.w = mw.w * bf2f(g4.w) + (1.f - mw.w) * xv.w;
    float ss = v.x * v.x + v.y * v.y + v.z * v.z + v.w * v.w;
#pragma unroll
    for (int off = 32; off; off >>= 1) ss += __shfl_xor(ss, off);
    __shared__ float red[4];
    if (lane == 0) red[wid] = ss;
    __syncthreads();
    ss = red[0] + red[1] + red[2] + red[3];
    float sc = rsqrtf(ss / (float)D + 1e-6f);
    float4 wv = ((const float4*)normw)[t];
    v.x *= sc * wv.x; v.y *= sc * wv.y; v.z *= sc * wv.z; v.w *= sc * wv.w;
    ((float4*)(out + base))[t] = v;
}

// ---------------------------------------------------------------------------
extern "C" void kernel_launch(void* const* d_in, const int* in_sizes, int n_in,
                              void* d_out, int out_size, void* d_ws, size_t ws_size,
                              hipStream_t stream) {
    const float* x = (const float*)d_in[0];
    const float* W1 = (const float*)d_in[1];
    const float* b1 = (const float*)d_in[2];
    const float* W2 = (const float*)d_in[3];
    const float* b2 = (const float*)d_in[4];
    const float* Wv = (const float*)d_in[5];
    const float* bv = (const float*)d_in[6];
    const float* mixw = (const float*)d_in[7];
    const float* normw = (const float*)d_in[8];
    float* out = (float*)d_out;

    const int L = 2048, D = 1024, INNER = 1536, BN4 = 4;
    const int M = BN4 * L;  // 8192

    // workspace carve
    char* w = (char*)d_ws;
    auto carve = [&](size_t bytes) {
        void* p = (void*)w;
        w += (bytes + 255) & ~(size_t)255;
        return p;
    };
    unsigned short* xbf = (unsigned short*)carve((size_t)M * D * 2);
    unsigned short* w1t = (unsigned short*)carve((size_t)INNER * D * 2);
    unsigned short* w2t = (unsigned short*)carve((size_t)3 * D * INNER * 2);
    unsigned short* wvt = (unsigned short*)carve((size_t)D * D * 2);
    unsigned short* h = (unsigned short*)carve((size_t)M * INNER * 2);
    unsigned short* qkg = (unsigned short*)carve((size_t)M * 3 * D * 2);
    unsigned short* vt = (unsigned short*)carve((size_t)BN4 * D * L * 2);
    unsigned short* pbuf = (unsigned short*)carve((size_t)BN4 * L * L * 2);
    float* lsum = (float*)carve((size_t)M * 4);  // softmax row sums
    unsigned short* gi = h;  // h is dead after GEMM2; reuse for gi [B][L][D]

    // 0) zero the row-sum accumulator
    zero_f32<<<M / 256, 256, 0, stream>>>(lsum, M);
    // 1) x -> bf16
    cvt_f32_bf16<<<(M * D) / 2048, 256, 0, stream>>>(x, xbf, (long long)M * D / 8);
    // 2-4) weights -> bf16, transposed to [N][K]
    transpose_cvt<<<dim3(INNER / 32, D / 32), 256, 0, stream>>>(W1, w1t, D, INNER);
    transpose_cvt<<<dim3(3 * D / 32, INNER / 32), 256, 0, stream>>>(W2, w2t, INNER, 3 * D);
    transpose_cvt<<<dim3(D / 32, D / 32), 256, 0, stream>>>(Wv, wvt, D, D);
    // 5) h = silu(x @ W1 + b1)     [M][INNER] bf16   (768 blocks, 3/CU)
    gemmk<0><<<dim3(768, 1, 1), 256, 0, stream>>>(xbf, D, w1t, D, D, h, INNER,
                                                  b1, 12);
    // 6) qkg = h @ W2 + b2         [M][3D] bf16      (768 blocks)
    gemm5<1><<<dim3(768, 1, 1), 512, 0, stream>>>(
        h, INNER, 0, w2t, INNER, 0, INNER, qkg, 3 * D, 0, b2, nullptr, 0,
        1.f, 24, nullptr, nullptr);
    // 7) vT = ((x @ Wv + bv)*sigmoid(g))^T  [B][D][L] bf16  (256 blocks)
    gemm5<2><<<dim3(256, 1, 1), 512, 0, stream>>>(
        xbf, D, 0, wvt, D, 0, D, vt, L, 0, bv, qkg + 2 * D, 3 * D,
        1.f, 8, nullptr, nullptr);
    // 8) P' = exp(min(q@k^T/32,80)) bf16 [B][L][L]; row sums -> lsum
    gemm5<5><<<dim3(128, 1, BN4), 512, 0, stream>>>(
        qkg, 3 * D, (long long)L * 3 * D, qkg + D, 3 * D, (long long)L * 3 * D,
        D, pbuf, L, (long long)L * L, nullptr, nullptr, 0,
        0.03125f, 16, nullptr, lsum);
    // 9) gi = (P' @ vT^T)/l  bf16 [B][L][D]   (256 blocks; gi reuses h)
    gemm5<6><<<dim3(64, 1, BN4), 512, 0, stream>>>(
        pbuf, L, (long long)L * L, vt, L, (long long)D * L, L, gi, D,
        (long long)L * D, nullptr, nullptr, 0, 1.f, 8, lsum, nullptr);
    // 10) out = rmsnorm(mix*gi + (1-mix)*x)
    mix_rmsnorm<<<M, 256, 0, stream>>>(gi, x, mixw, normw, out);
}

// Round 10
// 270.719 us; speedup vs baseline: 1.1986x; 1.0130x over previous
//
#include <hip/hip_runtime.h>
#include <hip/hip_bf16.h>
#include <stdint.h>

// ---------------------------------------------------------------------------
// SelectiveMixing: x->W1->silu->W2->(q,k,g); v=(x@Wv+bv)*sig(g);
// attn=softmax(qk^T/sqrt(D)); out=rmsnorm(mix*attn@v + (1-mix)*x)
// B=4, L=2048, D=1024, INNER=1536. bf16 MFMA, f32 accum.
// Softmax fused: P' = exp(min(s,80)) bf16 + f32 row sums (atomics); PV
// applies 1/l; fused mix+rmsnorm finishes.
// gemm8: m201-style 8-phase 256x256 GEMM (wave tile 128x64, B reg-cached,
//        counted vmcnt(4) at phases 4/8) — used where the grid packs (scores).
// gemm5: 256x128 4-phase GEMM for GEMM2/VGEMM/PV. gemmk: 128^2 for GEMM1.
// RULE: inside counted-vmcnt regions NO other VMEM op may issue.
// ---------------------------------------------------------------------------

typedef __bf16 bf16x8 __attribute__((ext_vector_type(8)));
typedef float f32x4 __attribute__((ext_vector_type(4)));

#define VM4 asm volatile("s_waitcnt vmcnt(4)" ::: "memory")
#define VM2 asm volatile("s_waitcnt vmcnt(2)" ::: "memory")
#define VM0 asm volatile("s_waitcnt vmcnt(0)" ::: "memory")
#define LGKM0 asm volatile("s_waitcnt lgkmcnt(0)" ::: "memory")
#define BAR __builtin_amdgcn_s_barrier()
#define SCB __builtin_amdgcn_sched_barrier(0)

__device__ __forceinline__ unsigned short f2bf(float f) {
    unsigned int u = __float_as_uint(f);
    u += 0x7fffu + ((u >> 16) & 1u);
    return (unsigned short)(u >> 16);
}
__device__ __forceinline__ float bf2f(unsigned short s) {
    return __uint_as_float(((unsigned int)s) << 16);
}
__device__ __forceinline__ void llds16(const void* g, void* l) {
    __builtin_amdgcn_global_load_lds(
        (const __attribute__((address_space(1))) void*)g,
        (__attribute__((address_space(3))) void*)l, 16, 0, 0);
}
__device__ __forceinline__ f32x4 MF(bf16x8 a, bf16x8 b, f32x4 c) {
    return __builtin_amdgcn_mfma_f32_16x16x32_bf16(a, b, c, 0, 0, 0);
}

// ---------------- zero fill ------------------------------------------------
__global__ __launch_bounds__(256) void zero_f32(float* __restrict__ p, int n) {
    int i = blockIdx.x * 256 + threadIdx.x;
    if (i < n) p[i] = 0.f;
}

// ---------------- elementwise: f32 -> bf16 (8 elems/thread) ----------------
__global__ __launch_bounds__(256) void cvt_f32_bf16(
    const float* __restrict__ in, unsigned short* __restrict__ out, long long n8) {
    long long i = (long long)blockIdx.x * 256 + threadIdx.x;
    if (i >= n8) return;
    float4 a = ((const float4*)in)[2 * i];
    float4 b = ((const float4*)in)[2 * i + 1];
    ushort4 p0, p1;
    p0.x = f2bf(a.x); p0.y = f2bf(a.y); p0.z = f2bf(a.z); p0.w = f2bf(a.w);
    p1.x = f2bf(b.x); p1.y = f2bf(b.y); p1.z = f2bf(b.z); p1.w = f2bf(b.w);
    ((ushort4*)out)[2 * i] = p0;
    ((ushort4*)out)[2 * i + 1] = p1;
}

// ---------------- transpose + convert: f32 [R][C] -> bf16 [C][R] -----------
__global__ __launch_bounds__(256) void transpose_cvt(
    const float* __restrict__ in, unsigned short* __restrict__ out, int R, int C) {
    __shared__ unsigned short tile[32][33];
    int c0 = blockIdx.x * 32, r0 = blockIdx.y * 32;
    int cc = threadIdx.x & 31, rr = threadIdx.x >> 5;
#pragma unroll
    for (int p = 0; p < 4; ++p) {
        int r = rr + p * 8;
        tile[r][cc] = f2bf(in[(size_t)(r0 + r) * C + c0 + cc]);
    }
    __syncthreads();
#pragma unroll
    for (int p = 0; p < 4; ++p) {
        int c = rr + p * 8;
        out[(size_t)(c0 + c) * R + r0 + cc] = tile[cc][c];
    }
}

// ---------------- gemm8: 8-phase 256x256 GEMM, C = A @ B^T -----------------
// 512 threads = 8 waves (2M x 4N), wave tile 128x64, BK=64.
// LDS: 2 buffers x (A 256x64 + B 256x64) bf16 = 128 KiB, XOR-swizzled.
// Per K-tile: 4 phases; phase q reads A M-frags {2q,2q+1} (4 ds_read) and,
// at q==0, all 8 B frags (reg-cached for the whole tile). Each phase stages
// one half-tile (2 gload_lds/thread) per the FIFO ledger:
//   hb=0: q0 A-h0(t+1)->Y  q1 A-h1(t+1)->Y  q2 B-h0(t+2)->X  q3 B-h1(t+2)->X
//   hb=1: q0 A-h0(t+2)->X  q1 A-h1(t+2)->X  q2 B-h0(t+3)->Y  q3 B-h1(t+3)->Y
// vmcnt(4) at phase 4/8 end retires {B(t+1),A(t+1)} / {B(t+2),A(t+2)};
// last iteration: vmcnt(0) at phase 4, nothing outstanding at phase 8.
// EPI 5: P' bf16 = exp(min(acc*scale,80)); atomicAdd row sums into stat.
__global__ __launch_bounds__(512, 1) void gemm8(
    const unsigned short* __restrict__ A, int lda, long long Abs,
    const unsigned short* __restrict__ B, int ldb, long long Bbs,
    int K,
    unsigned short* __restrict__ out, int ldo, long long Obs,
    float scale, int gx, float* __restrict__ stat) {
    __shared__ unsigned short lds[65536];  // X @0, Y @32768
    const int tid = threadIdx.x, lane = tid & 63, wid = tid >> 6;
    const int wr = wid >> 2, wc = wid & 3;  // 2M x 4N
    const int nwg = gridDim.x;
    const int bswz = ((int)blockIdx.x & 7) * (nwg >> 3) + ((int)blockIdx.x >> 3);
    const int bx = bswz % gx, by = bswz / gx;
    const int bm = by * 256, bn = bx * 256;
    const int z = blockIdx.z;
    A += (long long)z * Abs;
    B += (long long)z * Bbs;
    const int NT = K >> 6;  // even, >= 4

    const int sswz = ((tid & 7) ^ ((tid >> 3) & 7)) * 8;
    size_t agc[4], bgc[4];
#pragma unroll
    for (int c = 0; c < 4; ++c) {
        agc[c] = (size_t)(bm + c * 64 + (tid >> 3)) * lda + sswz;
        bgc[c] = (size_t)(bn + c * 64 + (tid >> 3)) * ldb + sswz;
    }
    const int wl = wid * 512;

    auto stA = [&](int t, int h, int buf) {
        const size_t k0 = (size_t)t << 6;
        llds16(A + agc[h * 2] + k0, &lds[buf + (h * 2) * 4096 + wl]);
        llds16(A + agc[h * 2 + 1] + k0, &lds[buf + (h * 2 + 1) * 4096 + wl]);
    };
    auto stB = [&](int t, int h, int buf) {
        const size_t k0 = (size_t)t << 6;
        llds16(B + bgc[h * 2] + k0, &lds[buf + 16384 + (h * 2) * 4096 + wl]);
        llds16(B + bgc[h * 2 + 1] + k0,
               &lds[buf + 16384 + (h * 2 + 1) * 4096 + wl]);
    };

    const int l15 = lane & 15, g4 = lane >> 4, l7 = lane & 7;
    const int x0 = (g4 ^ l7) * 8, x1 = ((4 + g4) ^ l7) * 8;
    const int ab = (wr * 128 + l15) * 64;           // A: + m*1024 + xs
    const int bbv = 16384 + (wc * 64 + l15) * 64;   // B: + j*1024 + xs
    constexpr int X = 0, Y = 32768;

    f32x4 acc[8][4] = {};

    // prologue: A(0),B(0) -> X; B(1) -> Y. vmcnt(4) leaves B(1) in flight.
    stA(0, 0, X); stA(0, 1, X); stB(0, 0, X); stB(0, 1, X);
    stB(1, 0, Y); stB(1, 1, Y);
    VM4;
    BAR; SCB;

    int t = 0;
    while (true) {
        const bool st2 = (t + 2) < NT;
#pragma unroll
        for (int hb = 0; hb < 2; ++hb) {
            const int buf = hb ? Y : X;
            bf16x8 bfr[4][2];
#pragma unroll
            for (int q = 0; q < 4; ++q) {
                // ---- ds reads for this phase
                if (q == 0) {
#pragma unroll
                    for (int j = 0; j < 4; ++j) {
                        bfr[j][0] = *(const bf16x8*)&lds[buf + bbv + j * 1024 + x0];
                        bfr[j][1] = *(const bf16x8*)&lds[buf + bbv + j * 1024 + x1];
                    }
                }
                bf16x8 af[2][2];
#pragma unroll
                for (int mq = 0; mq < 2; ++mq) {
                    af[mq][0] =
                        *(const bf16x8*)&lds[buf + ab + (q * 2 + mq) * 1024 + x0];
                    af[mq][1] =
                        *(const bf16x8*)&lds[buf + ab + (q * 2 + mq) * 1024 + x1];
                }
                // ---- stage one half-tile (FIFO ledger)
                if (hb == 0) {
                    if (q == 0) stA(t + 1, 0, Y);
                    else if (q == 1) stA(t + 1, 1, Y);
                    else if (q == 2) { if (st2) stB(t + 2, 0, X); }
                    else { if (st2) stB(t + 2, 1, X); }
                } else {
                    if (q == 0) { if (st2) stA(t + 2, 0, X); }
                    else if (q == 1) { if (st2) stA(t + 2, 1, X); }
                    else if (q == 2) { if (st2) stB(t + 3, 0, Y); }
                    else { if (st2) stB(t + 3, 1, Y); }
                }
                BAR;
                LGKM0; SCB;
                __builtin_amdgcn_s_setprio(1);
#pragma unroll
                for (int s = 0; s < 2; ++s)
#pragma unroll
                    for (int mq = 0; mq < 2; ++mq)
#pragma unroll
                        for (int j = 0; j < 4; ++j)
                            acc[q * 2 + mq][j] =
                                MF(af[mq][s], bfr[j][s], acc[q * 2 + mq][j]);
                __builtin_amdgcn_s_setprio(0);
                if (q == 3) {
                    if (hb == 0) { if (st2) { VM4; } else { VM0; } }
                    else if (st2) { VM4; }
                }
                if (hb == 1 && q == 3 && !st2) break;  // done; nothing in flight
                BAR; SCB;
            }
        }
        if (!st2) break;
        t += 2;
    }

    // --- epilogue: P' = exp(min(acc*scale,80)), row sums via atomics
    const int row0 = bm + wr * 128, col0 = bn + wc * 64;
    unsigned short* o = out + (size_t)z * Obs;
#pragma unroll
    for (int m = 0; m < 8; ++m) {
        const int mb = row0 + m * 16 + g4 * 4;
        float rs[4] = {0.f, 0.f, 0.f, 0.f};
#pragma unroll
        for (int j = 0; j < 4; ++j) {
            const int n = col0 + j * 16 + l15;
#pragma unroll
            for (int qq = 0; qq < 4; ++qq) {
                float p = __expf(fminf(acc[m][j][qq] * scale, 80.f));
                o[(size_t)(mb + qq) * ldo + n] = f2bf(p);
                rs[qq] += p;
            }
        }
#pragma unroll
        for (int qq = 0; qq < 4; ++qq) {
            float s = rs[qq];
            s += __shfl_xor(s, 1); s += __shfl_xor(s, 2);
            s += __shfl_xor(s, 4); s += __shfl_xor(s, 8);
            if (l15 == 0) atomicAdd(&stat[(size_t)z * 2048 + mb + qq], s);
        }
    }
}

// ---------------- gemm5: 256x128 pipelined GEMM, C = A @ B^T ---------------
// EPI 1: bf16 = acc+bias[n]
// EPI 2: vT bf16: out[(m>>11)*1024+n][m&2047] = (acc+bias[n])*sigmoid(gate)
// EPI 6: gi bf16 = acc / l[row]
template <int EPI>
__global__ __launch_bounds__(512, 1) void gemm5(
    const unsigned short* __restrict__ A, int lda, long long Abs,
    const unsigned short* __restrict__ B, int ldb, long long Bbs,
    int K,
    void* __restrict__ out, int ldo, long long Obs,
    const float* __restrict__ bias,
    const unsigned short* __restrict__ gate, int ldg,
    float scale, int gx,
    const float* __restrict__ bnd, float* __restrict__ stat) {
    __shared__ unsigned short lds[49152];  // X @0, Y @24576
    const int tid = threadIdx.x, lane = tid & 63, wid = tid >> 6;
    const int wr = wid >> 1, wc = wid & 1;
    const int nwg = gridDim.x;
    const int bswz = ((int)blockIdx.x & 7) * (nwg >> 3) + ((int)blockIdx.x >> 3);
    const int bx = bswz % gx, by = bswz / gx;
    const int bm = by * 256, bn = bx * 128;
    const int z = blockIdx.z;
    A += (long long)z * Abs;
    B += (long long)z * Bbs;
    const int NT = K >> 6;

    const int sswz = ((tid & 7) ^ ((tid >> 3) & 7)) * 8;
    size_t agc[4], bgc[2];
#pragma unroll
    for (int c = 0; c < 4; ++c)
        agc[c] = (size_t)(bm + c * 64 + (tid >> 3)) * lda + sswz;
#pragma unroll
    for (int c = 0; c < 2; ++c)
        bgc[c] = (size_t)(bn + c * 64 + (tid >> 3)) * ldb + sswz;
    const int wl = wid * 512;

    auto stA01 = [&](int t, int buf) {
        const size_t k0 = (size_t)t << 6;
        llds16(A + agc[0] + k0, &lds[buf + wl]);
        llds16(A + agc[1] + k0, &lds[buf + 4096 + wl]);
    };
    auto stA23 = [&](int t, int buf) {
        const size_t k0 = (size_t)t << 6;
        llds16(A + agc[2] + k0, &lds[buf + 8192 + wl]);
        llds16(A + agc[3] + k0, &lds[buf + 12288 + wl]);
    };
    auto stB = [&](int t, int buf) {
        const size_t k0 = (size_t)t << 6;
        llds16(B + bgc[0] + k0, &lds[buf + 16384 + wl]);
        llds16(B + bgc[1] + k0, &lds[buf + 20480 + wl]);
    };

    const int l15 = lane & 15, g4 = lane >> 4, l7 = lane & 7;
    const int x0 = (g4 ^ l7) * 8, x1 = ((4 + g4) ^ l7) * 8;
    const int ab = (wr * 64 + l15) * 64;
    const int bbv = 16384 + (wc * 64 + l15) * 64;
    constexpr int X = 0, Y = 24576;

    f32x4 acc[4][4] = {};

    stB(0, X); stA01(0, X); stA23(0, X); stB(1, Y);
    VM4;
    BAR; SCB;

    int t = 0;
    while (true) {
        const bool last = (t + 2) >= NT;
        bf16x8 bf[4][2], af[2][2];
        // ---- F0
#pragma unroll
        for (int j = 0; j < 4; ++j) {
            bf[j][0] = *(const bf16x8*)&lds[X + bbv + j * 1024 + x0];
            bf[j][1] = *(const bf16x8*)&lds[X + bbv + j * 1024 + x1];
        }
#pragma unroll
        for (int i = 0; i < 2; ++i) {
            af[i][0] = *(const bf16x8*)&lds[X + ab + i * 1024 + x0];
            af[i][1] = *(const bf16x8*)&lds[X + ab + i * 1024 + x1];
        }
        stA01(t + 1, Y);
        LGKM0; SCB;
        __builtin_amdgcn_s_setprio(1);
#pragma unroll
        for (int s = 0; s < 2; ++s)
#pragma unroll
            for (int i = 0; i < 2; ++i)
#pragma unroll
                for (int j = 0; j < 4; ++j)
                    acc[i][j] = MF(af[i][s], bf[j][s], acc[i][j]);
        __builtin_amdgcn_s_setprio(0);
        VM4;
        BAR; SCB;
        // ---- F1
#pragma unroll
        for (int i = 0; i < 2; ++i) {
            af[i][0] = *(const bf16x8*)&lds[X + ab + (2 + i) * 1024 + x0];
            af[i][1] = *(const bf16x8*)&lds[X + ab + (2 + i) * 1024 + x1];
        }
        stA23(t + 1, Y);
        if (!last) stB(t + 2, X);
        LGKM0; SCB;
        __builtin_amdgcn_s_setprio(1);
#pragma unroll
        for (int s = 0; s < 2; ++s)
#pragma unroll
            for (int i = 0; i < 2; ++i)
#pragma unroll
                for (int j = 0; j < 4; ++j)
                    acc[2 + i][j] = MF(af[i][s], bf[j][s], acc[2 + i][j]);
        __builtin_amdgcn_s_setprio(0);
        if (last) { VM2; } else { VM4; }
        BAR; SCB;
        // ---- F2
#pragma unroll
        for (int j = 0; j < 4; ++j) {
            bf[j][0] = *(const bf16x8*)&lds[Y + bbv + j * 1024 + x0];
            bf[j][1] = *(const bf16x8*)&lds[Y + bbv + j * 1024 + x1];
        }
#pragma unroll
        for (int i = 0; i < 2; ++i) {
            af[i][0] = *(const bf16x8*)&lds[Y + ab + i * 1024 + x0];
            af[i][1] = *(const bf16x8*)&lds[Y + ab + i * 1024 + x1];
        }
        if (!last) stA01(t + 2, X);
        LGKM0; SCB;
        __builtin_amdgcn_s_setprio(1);
#pragma unroll
        for (int s = 0; s < 2; ++s)
#pragma unroll
            for (int i = 0; i < 2; ++i)
#pragma unroll
                for (int j = 0; j < 4; ++j)
                    acc[i][j] = MF(af[i][s], bf[j][s], acc[i][j]);
        __builtin_amdgcn_s_setprio(0);
        if (last) { VM0; } else { VM4; }
        BAR; SCB;
        // ---- F3
#pragma unroll
        for (int i = 0; i < 2; ++i) {
            af[i][0] = *(const bf16x8*)&lds[Y + ab + (2 + i) * 1024 + x0];
            af[i][1] = *(const bf16x8*)&lds[Y + ab + (2 + i) * 1024 + x1];
        }
        if (!last) { stA23(t + 2, X); stB(t + 3, Y); }
        LGKM0; SCB;
        __builtin_amdgcn_s_setprio(1);
#pragma unroll
        for (int s = 0; s < 2; ++s)
#pragma unroll
            for (int i = 0; i < 2; ++i)
#pragma unroll
                for (int j = 0; j < 4; ++j)
                    acc[2 + i][j] = MF(af[i][s], bf[j][s], acc[2 + i][j]);
        __builtin_amdgcn_s_setprio(0);
        if (last) break;
        VM4;
        BAR; SCB;
        t += 2;
    }

    // --- epilogue
    const int row0 = bm + wr * 64, col0 = bn + wc * 64;
    if constexpr (EPI == 1) {
        unsigned short* o = (unsigned short*)out;
#pragma unroll
        for (int i = 0; i < 4; ++i) {
            const int mb = row0 + i * 16 + g4 * 4;
#pragma unroll
            for (int j = 0; j < 4; ++j) {
                const int n = col0 + j * 16 + l15;
                const float bs = bias[n];
#pragma unroll
                for (int q = 0; q < 4; ++q)
                    o[(size_t)(mb + q) * ldo + n] = f2bf(acc[i][j][q] + bs);
            }
        }
    } else if constexpr (EPI == 2) {
        unsigned short* o = (unsigned short*)out;
#pragma unroll
        for (int i = 0; i < 4; ++i) {
            const int mb = row0 + i * 16 + g4 * 4;
#pragma unroll
            for (int j = 0; j < 4; ++j) {
                const int n = col0 + j * 16 + l15;
                const float bs = bias[n];
                ushort4 pk;
                unsigned short* pku = (unsigned short*)&pk;
#pragma unroll
                for (int q = 0; q < 4; ++q) {
                    int m = mb + q;
                    float g = bf2f(gate[(size_t)m * ldg + n]);
                    pku[q] = f2bf((acc[i][j][q] + bs) / (1.f + __expf(-g)));
                }
                size_t oi = ((size_t)(mb >> 11) * 1024 + n) * 2048 + (mb & 2047);
                *(ushort4*)(o + oi) = pk;
            }
        }
    } else {  // EPI == 6: gi bf16 = acc / l[row]
        unsigned short* o = (unsigned short*)out + (size_t)z * Obs;
        const float* ls = bnd + (size_t)z * 2048;
#pragma unroll
        for (int i = 0; i < 4; ++i) {
            const int mb = row0 + i * 16 + g4 * 4;
            float invl[4];
#pragma unroll
            for (int q = 0; q < 4; ++q) invl[q] = 1.f / ls[mb + q];
#pragma unroll
            for (int j = 0; j < 4; ++j) {
                const int n = col0 + j * 16 + l15;
#pragma unroll
                for (int q = 0; q < 4; ++q)
                    o[(size_t)(mb + q) * ldo + n] = f2bf(acc[i][j][q] * invl[q]);
            }
        }
    }
}

// ---------------- gemmk: 128x128 ring-3 GEMM (GEMM1 only) ------------------
template <int EPI>
__global__ __launch_bounds__(256, 3) void gemmk(
    const unsigned short* __restrict__ A, int lda,
    const unsigned short* __restrict__ B, int ldb,
    int K, void* __restrict__ out, int ldo,
    const float* __restrict__ bias, int gx) {
    __shared__ unsigned short lds[24576];
    const int tid = threadIdx.x, lane = tid & 63, wid = tid >> 6;
    const int nwg = gridDim.x;
    const int bswz = ((int)blockIdx.x & 7) * (nwg >> 3) + ((int)blockIdx.x >> 3);
    const int bx = bswz % gx, by = bswz / gx;
    const int bm = by * 128, bn = bx * 128;
    const int NT = K >> 5;

    const int srow = tid >> 2;
    const int sswz = ((tid & 3) ^ ((tid >> 3) & 3)) * 8;
    size_t ag[2], bg[2];
    ag[0] = (size_t)(bm + srow) * lda + sswz;
    ag[1] = (size_t)(bm + 64 + srow) * lda + sswz;
    bg[0] = (size_t)(bn + srow) * ldb + sswz;
    bg[1] = (size_t)(bn + 64 + srow) * ldb + sswz;
    const int wl = wid * 512;

    auto stage = [&](int t, int bb) {
        const size_t k0 = (size_t)t << 5;
        llds16(A + ag[0] + k0, &lds[bb + wl]);
        llds16(A + ag[1] + k0, &lds[bb + 2048 + wl]);
        llds16(B + bg[0] + k0, &lds[bb + 4096 + wl]);
        llds16(B + bg[1] + k0, &lds[bb + 6144 + wl]);
    };

    const int wr = wid >> 1, wc = wid & 1;
    const int l15 = lane & 15, g4 = lane >> 4;
    const int fswz = (g4 ^ ((l15 >> 1) & 3)) * 8;
    const int aoff = (wr * 64 + l15) * 32 + fswz;
    const int boff = 4096 + (wc * 64 + l15) * 32 + fswz;

    f32x4 acc[4][4] = {};
    stage(0, 0);
    stage(1, 8192);
    VM4; BAR;

    int bb = 0;
    for (int t = 0; t < NT; ++t) {
        const bool st = (t + 2) < NT;
        if (st) {
            const int tgt = (bb >= 8192) ? bb - 8192 : bb + 16384;
            stage(t + 2, tgt);
        }
        SCB;
        bf16x8 af[4], bf[4];
#pragma unroll
        for (int i = 0; i < 4; ++i) {
            af[i] = *(const bf16x8*)&lds[bb + aoff + i * 512];
            bf[i] = *(const bf16x8*)&lds[bb + boff + i * 512];
        }
#pragma unroll
        for (int i = 0; i < 4; ++i)
#pragma unroll
            for (int j = 0; j < 4; ++j)
                acc[i][j] = MF(af[i], bf[j], acc[i][j]);
        LGKM0;
        if (st) { VM4; } else { VM0; }
        BAR;
        bb = (bb == 16384) ? 0 : bb + 8192;
    }

    const int row0 = bm + wr * 64, col0 = bn + wc * 64;
#pragma unroll
    for (int i = 0; i < 4; ++i) {
#pragma unroll
        for (int j = 0; j < 4; ++j) {
            const int n = col0 + j * 16 + l15;
            const int mb = row0 + i * 16 + g4 * 4;
            f32x4 v = acc[i][j];
            float bs = bias[n];
            unsigned short* o = (unsigned short*)out;
#pragma unroll
            for (int q = 0; q < 4; ++q) {
                float val = v[q] + bs;
                if constexpr (EPI == 0) val = val / (1.f + __expf(-val));
                o[(size_t)(mb + q) * ldo + n] = f2bf(val);
            }
        }
    }
}

// ---------------- fused mix + RMSNorm: out f32 [row][1024] ----------------
__global__ __launch_bounds__(256) void mix_rmsnorm(
    const unsigned short* __restrict__ gi, const float* __restrict__ x,
    const float* __restrict__ mixw, const float* __restrict__ normw,
    float* __restrict__ out) {
    const int D = 1024;
    const size_t base = (size_t)blockIdx.x * D;
    const int t = threadIdx.x, lane = t & 63, wid = t >> 6;
    ushort4 g4 = ((const ushort4*)(gi + base))[t];
    float4 xv = ((const float4*)(x + base))[t];
    float4 mw = ((const float4*)mixw)[t];
    float4 v;
    v.x = mw.x * bf2f(g4.x) + (1.f - mw.x) * xv.x;
    v.y = mw.y * bf2f(g4.y) + (1.f - mw.y) * xv.y;
    v.z = mw.z * bf2f(g4.z) + (1.f - mw.z) * xv.z;
    v.w = mw.w * bf2f(g4.w) + (1.f - mw.w) * xv.w;
    float ss = v.x * v.x + v.y * v.y + v.z * v.z + v.w * v.w;
#pragma unroll
    for (int off = 32; off; off >>= 1) ss += __shfl_xor(ss, off);
    __shared__ float red[4];
    if (lane == 0) red[wid] = ss;
    __syncthreads();
    ss = red[0] + red[1] + red[2] + red[3];
    float sc = rsqrtf(ss / (float)D + 1e-6f);
    float4 wv = ((const float4*)normw)[t];
    v.x *= sc * wv.x; v.y *= sc * wv.y; v.z *= sc * wv.z; v.w *= sc * wv.w;
    ((float4*)(out + base))[t] = v;
}

// ---------------------------------------------------------------------------
extern "C" void kernel_launch(void* const* d_in, const int* in_sizes, int n_in,
                              void* d_out, int out_size, void* d_ws, size_t ws_size,
                              hipStream_t stream) {
    const float* x = (const float*)d_in[0];
    const float* W1 = (const float*)d_in[1];
    const float* b1 = (const float*)d_in[2];
    const float* W2 = (const float*)d_in[3];
    const float* b2 = (const float*)d_in[4];
    const float* Wv = (const float*)d_in[5];
    const float* bv = (const float*)d_in[6];
    const float* mixw = (const float*)d_in[7];
    const float* normw = (const float*)d_in[8];
    float* out = (float*)d_out;

    const int L = 2048, D = 1024, INNER = 1536, BN4 = 4;
    const int M = BN4 * L;  // 8192

    // workspace carve
    char* w = (char*)d_ws;
    auto carve = [&](size_t bytes) {
        void* p = (void*)w;
        w += (bytes + 255) & ~(size_t)255;
        return p;
    };
    unsigned short* xbf = (unsigned short*)carve((size_t)M * D * 2);
    unsigned short* w1t = (unsigned short*)carve((size_t)INNER * D * 2);
    unsigned short* w2t = (unsigned short*)carve((size_t)3 * D * INNER * 2);
    unsigned short* wvt = (unsigned short*)carve((size_t)D * D * 2);
    unsigned short* h = (unsigned short*)carve((size_t)M * INNER * 2);
    unsigned short* qkg = (unsigned short*)carve((size_t)M * 3 * D * 2);
    unsigned short* vt = (unsigned short*)carve((size_t)BN4 * D * L * 2);
    unsigned short* pbuf = (unsigned short*)carve((size_t)BN4 * L * L * 2);
    float* lsum = (float*)carve((size_t)M * 4);  // softmax row sums
    unsigned short* gi = h;  // h dead after GEMM2; reuse for gi [B][L][D]

    // 0) zero the row-sum accumulator
    zero_f32<<<M / 256, 256, 0, stream>>>(lsum, M);
    // 1) x -> bf16
    cvt_f32_bf16<<<(M * D) / 2048, 256, 0, stream>>>(x, xbf, (long long)M * D / 8);
    // 2-4) weights -> bf16, transposed to [N][K]
    transpose_cvt<<<dim3(INNER / 32, D / 32), 256, 0, stream>>>(W1, w1t, D, INNER);
    transpose_cvt<<<dim3(3 * D / 32, INNER / 32), 256, 0, stream>>>(W2, w2t, INNER, 3 * D);
    transpose_cvt<<<dim3(D / 32, D / 32), 256, 0, stream>>>(Wv, wvt, D, D);
    // 5) h = silu(x @ W1 + b1)     [M][INNER] bf16   (768 blocks, 3/CU)
    gemmk<0><<<dim3(768, 1, 1), 256, 0, stream>>>(xbf, D, w1t, D, D, h, INNER,
                                                  b1, 12);
    // 6) qkg = h @ W2 + b2         [M][3D] bf16      (768 blocks)
    gemm5<1><<<dim3(768, 1, 1), 512, 0, stream>>>(
        h, INNER, 0, w2t, INNER, 0, INNER, qkg, 3 * D, 0, b2, nullptr, 0,
        1.f, 24, nullptr, nullptr);
    // 7) vT = ((x @ Wv + bv)*sigmoid(g))^T  [B][D][L] bf16  (256 blocks)
    gemm5<2><<<dim3(256, 1, 1), 512, 0, stream>>>(
        xbf, D, 0, wvt, D, 0, D, vt, L, 0, bv, qkg + 2 * D, 3 * D,
        1.f, 8, nullptr, nullptr);
    // 8) P' = exp(min(q@k^T/32,80)) bf16 [B][L][L]; row sums -> lsum
    //    8-phase 256x256 kernel: 8x8 grid x 4 batches = 256 blocks (1 wave)
    gemm8<<<dim3(64, 1, BN4), 512, 0, stream>>>(
        qkg, 3 * D, (long long)L * 3 * D, qkg + D, 3 * D, (long long)L * 3 * D,
        D, pbuf, L, (long long)L * L, 0.03125f, 8, lsum);
    // 9) gi = (P' @ vT^T)/l  bf16 [B][L][D]   (256 blocks)
    gemm5<6><<<dim3(64, 1, BN4), 512, 0, stream>>>(
        pbuf, L, (long long)L * L, vt, L, (long long)D * L, L, gi, D,
        (long long)L * D, nullptr, nullptr, 0, 1.f, 8, lsum, nullptr);
    // 10) out = rmsnorm(mix*gi + (1-mix)*x)
    mix_rmsnorm<<<M, 256, 0, stream>>>(gi, x, mixw, normw, out);
}